// Round 1
// baseline (3064.303 us; speedup 1.0000x reference)
//
#include <hip/hip_runtime.h>

#define CIN 128
#define CH 256
#define COUT 128
#define BN_EPS 1e-5f

__device__ __forceinline__ void fma4(float4& a, float s, const float4& b) {
    a.x = fmaf(s, b.x, a.x);
    a.y = fmaf(s, b.y, a.y);
    a.z = fmaf(s, b.z, a.z);
    a.w = fmaf(s, b.w, a.w);
}

// deg[i] = 1 (self loop); zero BN stats accumulators
__global__ void k_init(float* __restrict__ deg, float* __restrict__ stats, int N) {
    int i = blockIdx.x * 256 + threadIdx.x;
    if (i < N) deg[i] = 1.0f;
    if (i < 512) stats[i] = 0.0f;
}

__global__ void k_deg(const int* __restrict__ dst, float* __restrict__ deg, int E) {
    int e = blockIdx.x * 256 + threadIdx.x;
    if (e < E) unsafeAtomicAdd(&deg[dst[e]], 1.0f);
}

__global__ void k_dinv(float* __restrict__ deg, int N) {
    int i = blockIdx.x * 256 + threadIdx.x;
    if (i < N) deg[i] = rsqrtf(deg[i]);
}

// out[i][:] = x[i][:] * dinv[i]^2 (+ bias), 128 channels as 32 float4
__global__ void k_selfloop(const float4* __restrict__ x, const float* __restrict__ dinv,
                           const float4* __restrict__ bias4, float4* __restrict__ out, int N) {
    int idx = blockIdx.x * 256 + threadIdx.x;
    if (idx >= N * 32) return;
    int row = idx >> 5;
    int c = idx & 31;
    float di = dinv[row];
    float w = di * di;
    float4 v = x[idx];
    float4 o;
    if (bias4) {
        float4 b = bias4[c];
        o.x = fmaf(v.x, w, b.x); o.y = fmaf(v.y, w, b.y);
        o.z = fmaf(v.z, w, b.z); o.w = fmaf(v.w, w, b.w);
    } else {
        o.x = v.x * w; o.y = v.y * w; o.z = v.z * w; o.w = v.w * w;
    }
    out[idx] = o;
}

// per edge: out[dst] += x[src] * dinv[src]*dinv[dst]; 32 threads/edge, 4 ch each
__global__ void k_scatter(const float4* __restrict__ x, const int* __restrict__ src,
                          const int* __restrict__ dst, const float* __restrict__ dinv,
                          float* __restrict__ out, int E) {
    int t = blockIdx.x * 256 + threadIdx.x;
    int e = t >> 5;
    int c = t & 31;
    if (e >= E) return;
    int s = src[e];
    int d = dst[e];
    float w = dinv[s] * dinv[d];
    float4 v = x[s * 32 + c];
    float* o = out + (size_t)d * 128 + c * 4;
    unsafeAtomicAdd(o + 0, v.x * w);
    unsafeAtomicAdd(o + 1, v.y * w);
    unsafeAtomicAdd(o + 2, v.z * w);
    unsafeAtomicAdd(o + 3, v.w * w);
}

// X1[N,256] = A[N,128] @ W1[128,256] + b1. Wave handles 4 rows; lane covers 4 cols.
__global__ __launch_bounds__(256) void k_gemm1(const float* __restrict__ A,
                                               const float4* __restrict__ W4,
                                               const float4* __restrict__ b4,
                                               float4* __restrict__ X, int N) {
    __shared__ float sa[16][128];
    int w = threadIdx.x >> 6;
    int lane = threadIdx.x & 63;
    int row0 = blockIdx.x * 16 + w * 4;
    for (int r = 0; r < 4; ++r) {
        int row = row0 + r;
        float2 v = make_float2(0.f, 0.f);
        if (row < N) v = *(const float2*)(A + (size_t)row * 128 + lane * 2);
        sa[w * 4 + r][lane * 2] = v.x;
        sa[w * 4 + r][lane * 2 + 1] = v.y;
    }
    __syncthreads();
    float4 bv = b4[lane];
    float4 acc0 = bv, acc1 = bv, acc2 = bv, acc3 = bv;
    for (int k = 0; k < 128; ++k) {
        float4 wv = W4[k * 64 + lane];
        fma4(acc0, sa[w * 4 + 0][k], wv);
        fma4(acc1, sa[w * 4 + 1][k], wv);
        fma4(acc2, sa[w * 4 + 2][k], wv);
        fma4(acc3, sa[w * 4 + 3][k], wv);
    }
    if (row0 + 0 < N) X[(size_t)(row0 + 0) * 64 + lane] = acc0;
    if (row0 + 1 < N) X[(size_t)(row0 + 1) * 64 + lane] = acc1;
    if (row0 + 2 < N) X[(size_t)(row0 + 2) * 64 + lane] = acc2;
    if (row0 + 3 < N) X[(size_t)(row0 + 3) * 64 + lane] = acc3;
}

// partial per-channel sum/sumsq of X1[N,256] -> stats[0:256]=sum, [256:512]=sumsq
__global__ void k_bnstats(const float* __restrict__ X, float* __restrict__ stats,
                          int N, int rpb) {
    int c = threadIdx.x; // 256 threads = 256 channels
    int r0 = blockIdx.x * rpb;
    float s = 0.f, sq = 0.f;
    for (int i = 0; i < rpb; ++i) {
        int r = r0 + i;
        if (r < N) {
            float v = X[(size_t)r * 256 + c];
            s += v;
            sq = fmaf(v, v, sq);
        }
    }
    unsafeAtomicAdd(&stats[c], s);
    unsafeAtomicAdd(&stats[256 + c], sq);
}

__global__ void k_bnfinal(const float* __restrict__ stats, const float* __restrict__ gamma,
                          const float* __restrict__ beta, float* __restrict__ scsh, int N) {
    int c = threadIdx.x;
    float invN = 1.0f / (float)N;
    float mean = stats[c] * invN;
    float var = stats[256 + c] * invN - mean * mean;
    var = fmaxf(var, 0.f);
    float inv = rsqrtf(var + BN_EPS);
    float sc = gamma[c] * inv;
    scsh[c] = sc;
    scsh[256 + c] = fmaf(-mean, sc, beta[c]);
}

// Y[N,128] = relu(X1*scale+shift) @ W2[256,128]. Wave handles 4 rows; lane covers 2 cols.
__global__ __launch_bounds__(256) void k_gemm2(const float4* __restrict__ X4,
                                               const float4* __restrict__ scale4,
                                               const float4* __restrict__ shift4,
                                               const float2* __restrict__ W2v,
                                               float2* __restrict__ Y, int N) {
    __shared__ float sa[16][256];
    int w = threadIdx.x >> 6;
    int lane = threadIdx.x & 63;
    int row0 = blockIdx.x * 16 + w * 4;
    float4 sc = scale4[lane];
    float4 sh = shift4[lane];
    for (int r = 0; r < 4; ++r) {
        int row = row0 + r;
        float4 v = (row < N) ? X4[(size_t)row * 64 + lane] : make_float4(0.f, 0.f, 0.f, 0.f);
        float4 u;
        u.x = fmaxf(fmaf(v.x, sc.x, sh.x), 0.f);
        u.y = fmaxf(fmaf(v.y, sc.y, sh.y), 0.f);
        u.z = fmaxf(fmaf(v.z, sc.z, sh.z), 0.f);
        u.w = fmaxf(fmaf(v.w, sc.w, sh.w), 0.f);
        *(float4*)&sa[w * 4 + r][lane * 4] = u;
    }
    __syncthreads();
    float2 acc[4];
    for (int r = 0; r < 4; ++r) acc[r] = make_float2(0.f, 0.f);
    for (int k = 0; k < 256; ++k) {
        float2 wv = W2v[k * 64 + lane];
        for (int r = 0; r < 4; ++r) {
            float a = sa[w * 4 + r][k];
            acc[r].x = fmaf(a, wv.x, acc[r].x);
            acc[r].y = fmaf(a, wv.y, acc[r].y);
        }
    }
    for (int r = 0; r < 4; ++r) {
        int row = row0 + r;
        if (row < N) Y[(size_t)row * 64 + lane] = acc[r];
    }
}

extern "C" void kernel_launch(void* const* d_in, const int* in_sizes, int n_in,
                              void* d_out, int out_size, void* d_ws, size_t ws_size,
                              hipStream_t stream) {
    const float* nf    = (const float*)d_in[0];
    const int*   ei    = (const int*)d_in[1];
    const float* W1    = (const float*)d_in[2];
    const float* b1    = (const float*)d_in[3];
    const float* gamma = (const float*)d_in[4];
    const float* beta  = (const float*)d_in[5];
    const float* W2    = (const float*)d_in[6];
    const float* b2    = (const float*)d_in[7];
    float* out = (float*)d_out;

    const int N = in_sizes[0] / CIN;      // 50000
    const int E = in_sizes[1] / 2;        // 800000
    const int* src = ei;
    const int* dst = ei + E;

    char* ws = (char*)d_ws;
    auto align256 = [](size_t x) { return (x + 255) & ~(size_t)255; };
    size_t off = 0;
    float* dinv = (float*)(ws + off);  off += align256((size_t)N * 4);        // deg -> dinv in place
    float* stats = (float*)(ws + off); off += align256(512 * 4);              // sum[256], sumsq[256]
    float* scsh = (float*)(ws + off);  off += align256(512 * 4);              // scale[256], shift[256]
    float* agg1 = (float*)(ws + off);  off += align256((size_t)N * CIN * 4);  // S @ x   [N,128]
    float* x1 = (float*)(ws + off);    off += align256((size_t)N * CH * 4);   // layer1 out [N,256]
    float* y = (float*)(ws + off);     off += align256((size_t)N * COUT * 4); // bnrelu(x1)@W2 [N,128]

    // degree + norm
    k_init<<<(N + 255) / 256, 256, 0, stream>>>(dinv, stats, N);
    k_deg<<<(E + 255) / 256, 256, 0, stream>>>(dst, dinv, E);
    k_dinv<<<(N + 255) / 256, 256, 0, stream>>>(dinv, N);

    // layer 1 aggregation: agg1 = S @ node_feat
    k_selfloop<<<(N * 32 + 255) / 256, 256, 0, stream>>>(
        (const float4*)nf, dinv, nullptr, (float4*)agg1, N);
    k_scatter<<<(E * 32 + 255) / 256, 256, 0, stream>>>(
        (const float4*)nf, src, dst, dinv, agg1, E);

    // x1 = agg1 @ W1 + b1
    k_gemm1<<<(N + 15) / 16, 256, 0, stream>>>(
        agg1, (const float4*)W1, (const float4*)b1, (float4*)x1, N);

    // batch norm stats + scale/shift
    int nblk = 200;
    int rpb = (N + nblk - 1) / nblk;
    k_bnstats<<<nblk, 256, 0, stream>>>(x1, stats, N, rpb);
    k_bnfinal<<<1, 256, 0, stream>>>(stats, gamma, beta, scsh, N);

    // y = relu(bn(x1)) @ W2
    k_gemm2<<<(N + 15) / 16, 256, 0, stream>>>(
        (const float4*)x1, (const float4*)scsh, (const float4*)(scsh + 256),
        (const float2*)W2, (float2*)y, N);

    // out = S @ y + b2
    k_selfloop<<<(N * 32 + 255) / 256, 256, 0, stream>>>(
        (const float4*)y, dinv, (const float4*)b2, (float4*)out, N);
    k_scatter<<<(E * 32 + 255) / 256, 256, 0, stream>>>(
        (const float4*)y, src, dst, dinv, out, E);
}

// Round 2
// 529.904 us; speedup vs baseline: 5.7827x; 5.7827x over previous
//
#include <hip/hip_runtime.h>

#define CIN 128
#define CH 256
#define COUT 128
#define BN_EPS 1e-5f

__device__ __forceinline__ void fma4(float4& a, float s, const float4& b) {
    a.x = fmaf(s, b.x, a.x);
    a.y = fmaf(s, b.y, a.y);
    a.z = fmaf(s, b.z, a.z);
    a.w = fmaf(s, b.w, a.w);
}

// zero in-degree counters and BN stats accumulators
__global__ void k_init(int* __restrict__ degi, float* __restrict__ stats, int N) {
    int i = blockIdx.x * 256 + threadIdx.x;
    if (i < N) degi[i] = 0;
    if (i < 512) stats[i] = 0.0f;
}

__global__ void k_deg(const int* __restrict__ dst, int* __restrict__ degi, int E) {
    int e = blockIdx.x * 256 + threadIdx.x;
    if (e < E) atomicAdd(&degi[dst[e]], 1);
}

// dinv = rsqrt(indeg + 1)  (self-loop included in norm degree)
__global__ void k_dinv(const int* __restrict__ degi, float* __restrict__ dinv, int N) {
    int i = blockIdx.x * 256 + threadIdx.x;
    if (i < N) dinv[i] = rsqrtf((float)(degi[i] + 1));
}

// per-block sums of degi
__global__ void k_scan1(const int* __restrict__ degi, int* __restrict__ blocksum, int N) {
    __shared__ int s[256];
    int i = blockIdx.x * 256 + threadIdx.x;
    s[threadIdx.x] = (i < N) ? degi[i] : 0;
    __syncthreads();
    for (int st = 128; st > 0; st >>= 1) {
        if (threadIdx.x < st) s[threadIdx.x] += s[threadIdx.x + st];
        __syncthreads();
    }
    if (threadIdx.x == 0) blocksum[blockIdx.x] = s[0];
}

// exclusive scan of block sums (nb <= 256); also rowstart[N] = E
__global__ void k_scan2(int* __restrict__ blocksum, int nb,
                        int* __restrict__ rowstart, int N, int E) {
    __shared__ int s[256];
    int v = (threadIdx.x < nb) ? blocksum[threadIdx.x] : 0;
    s[threadIdx.x] = v;
    __syncthreads();
    for (int st = 1; st < 256; st <<= 1) {
        int t = (threadIdx.x >= st) ? s[threadIdx.x - st] : 0;
        __syncthreads();
        s[threadIdx.x] += t;
        __syncthreads();
    }
    if (threadIdx.x < nb) blocksum[threadIdx.x] = s[threadIdx.x] - v;  // exclusive
    if (threadIdx.x == 0) rowstart[N] = E;
}

// within-block exclusive scan + block offset -> rowstart, cursor
__global__ void k_scan3(const int* __restrict__ degi, const int* __restrict__ blockoff,
                        int* __restrict__ rowstart, int* __restrict__ cursor, int N) {
    __shared__ int s[256];
    int i = blockIdx.x * 256 + threadIdx.x;
    int v = (i < N) ? degi[i] : 0;
    s[threadIdx.x] = v;
    __syncthreads();
    for (int st = 1; st < 256; st <<= 1) {
        int t = (threadIdx.x >= st) ? s[threadIdx.x - st] : 0;
        __syncthreads();
        s[threadIdx.x] += t;
        __syncthreads();
    }
    if (i < N) {
        int ex = s[threadIdx.x] - v + blockoff[blockIdx.x];
        rowstart[i] = ex;
        cursor[i] = ex;
    }
}

// place each edge into its dst bucket; precompute normalized weight
__global__ void k_fill(const int* __restrict__ src, const int* __restrict__ dst,
                       const float* __restrict__ dinv, int* __restrict__ cursor,
                       int* __restrict__ csr_src, float* __restrict__ csr_w, int E) {
    int e = blockIdx.x * 256 + threadIdx.x;
    if (e >= E) return;
    int s = src[e];
    int d = dst[e];
    int pos = atomicAdd(&cursor[d], 1);
    csr_src[pos] = s;
    csr_w[pos] = dinv[s] * dinv[d];
}

// out[r] = dinv[r]^2 * x[r] (+bias) + sum_e w_e * x[src_e]; 32 threads/row, float4 each
__global__ __launch_bounds__(256) void k_gather(const float4* __restrict__ x,
                                                const int* __restrict__ rowstart,
                                                const int* __restrict__ csr_src,
                                                const float* __restrict__ csr_w,
                                                const float* __restrict__ dinv,
                                                const float4* __restrict__ bias4,
                                                float4* __restrict__ out, int N) {
    int t = blockIdx.x * 256 + threadIdx.x;
    int r = t >> 5;
    int c = t & 31;
    if (r >= N) return;
    float di = dinv[r];
    float w0 = di * di;
    float4 v = x[(size_t)r * 32 + c];
    float4 acc;
    if (bias4) {
        float4 b = bias4[c];
        acc.x = fmaf(v.x, w0, b.x); acc.y = fmaf(v.y, w0, b.y);
        acc.z = fmaf(v.z, w0, b.z); acc.w = fmaf(v.w, w0, b.w);
    } else {
        acc.x = v.x * w0; acc.y = v.y * w0; acc.z = v.z * w0; acc.w = v.w * w0;
    }
    int e0 = rowstart[r], e1 = rowstart[r + 1];
    int e = e0;
    for (; e + 1 < e1; e += 2) {
        int sA = csr_src[e];
        int sB = csr_src[e + 1];
        float wA = csr_w[e];
        float wB = csr_w[e + 1];
        float4 xa = x[(size_t)sA * 32 + c];
        float4 xb = x[(size_t)sB * 32 + c];
        fma4(acc, wA, xa);
        fma4(acc, wB, xb);
    }
    if (e < e1) {
        int sA = csr_src[e];
        float wA = csr_w[e];
        float4 xa = x[(size_t)sA * 32 + c];
        fma4(acc, wA, xa);
    }
    out[(size_t)r * 32 + c] = acc;
}

// X1[N,256] = A[N,128] @ W1[128,256] + b1. Wave handles 4 rows; lane covers 4 cols.
__global__ __launch_bounds__(256) void k_gemm1(const float* __restrict__ A,
                                               const float4* __restrict__ W4,
                                               const float4* __restrict__ b4,
                                               float4* __restrict__ X, int N) {
    __shared__ float sa[16][128];
    int w = threadIdx.x >> 6;
    int lane = threadIdx.x & 63;
    int row0 = blockIdx.x * 16 + w * 4;
    for (int r = 0; r < 4; ++r) {
        int row = row0 + r;
        float2 v = make_float2(0.f, 0.f);
        if (row < N) v = *(const float2*)(A + (size_t)row * 128 + lane * 2);
        sa[w * 4 + r][lane * 2] = v.x;
        sa[w * 4 + r][lane * 2 + 1] = v.y;
    }
    __syncthreads();
    float4 bv = b4[lane];
    float4 acc0 = bv, acc1 = bv, acc2 = bv, acc3 = bv;
    for (int k = 0; k < 128; ++k) {
        float4 wv = W4[k * 64 + lane];
        fma4(acc0, sa[w * 4 + 0][k], wv);
        fma4(acc1, sa[w * 4 + 1][k], wv);
        fma4(acc2, sa[w * 4 + 2][k], wv);
        fma4(acc3, sa[w * 4 + 3][k], wv);
    }
    if (row0 + 0 < N) X[(size_t)(row0 + 0) * 64 + lane] = acc0;
    if (row0 + 1 < N) X[(size_t)(row0 + 1) * 64 + lane] = acc1;
    if (row0 + 2 < N) X[(size_t)(row0 + 2) * 64 + lane] = acc2;
    if (row0 + 3 < N) X[(size_t)(row0 + 3) * 64 + lane] = acc3;
}

// partial per-channel sum/sumsq of X1[N,256] -> stats[0:256]=sum, [256:512]=sumsq
__global__ void k_bnstats(const float* __restrict__ X, float* __restrict__ stats,
                          int N, int rpb) {
    int c = threadIdx.x;
    int r0 = blockIdx.x * rpb;
    float s = 0.f, sq = 0.f;
    for (int i = 0; i < rpb; ++i) {
        int r = r0 + i;
        if (r < N) {
            float v = X[(size_t)r * 256 + c];
            s += v;
            sq = fmaf(v, v, sq);
        }
    }
    unsafeAtomicAdd(&stats[c], s);
    unsafeAtomicAdd(&stats[256 + c], sq);
}

__global__ void k_bnfinal(const float* __restrict__ stats, const float* __restrict__ gamma,
                          const float* __restrict__ beta, float* __restrict__ scsh, int N) {
    int c = threadIdx.x;
    float invN = 1.0f / (float)N;
    float mean = stats[c] * invN;
    float var = stats[256 + c] * invN - mean * mean;
    var = fmaxf(var, 0.f);
    float inv = rsqrtf(var + BN_EPS);
    float sc = gamma[c] * inv;
    scsh[c] = sc;
    scsh[256 + c] = fmaf(-mean, sc, beta[c]);
}

// Y[N,128] = relu(X1*scale+shift) @ W2[256,128]. Wave handles 4 rows; lane covers 2 cols.
__global__ __launch_bounds__(256) void k_gemm2(const float4* __restrict__ X4,
                                               const float4* __restrict__ scale4,
                                               const float4* __restrict__ shift4,
                                               const float2* __restrict__ W2v,
                                               float2* __restrict__ Y, int N) {
    __shared__ float sa[16][256];
    int w = threadIdx.x >> 6;
    int lane = threadIdx.x & 63;
    int row0 = blockIdx.x * 16 + w * 4;
    float4 sc = scale4[lane];
    float4 sh = shift4[lane];
    for (int r = 0; r < 4; ++r) {
        int row = row0 + r;
        float4 v = (row < N) ? X4[(size_t)row * 64 + lane] : make_float4(0.f, 0.f, 0.f, 0.f);
        float4 u;
        u.x = fmaxf(fmaf(v.x, sc.x, sh.x), 0.f);
        u.y = fmaxf(fmaf(v.y, sc.y, sh.y), 0.f);
        u.z = fmaxf(fmaf(v.z, sc.z, sh.z), 0.f);
        u.w = fmaxf(fmaf(v.w, sc.w, sh.w), 0.f);
        *(float4*)&sa[w * 4 + r][lane * 4] = u;
    }
    __syncthreads();
    float2 acc[4];
    for (int r = 0; r < 4; ++r) acc[r] = make_float2(0.f, 0.f);
    for (int k = 0; k < 256; ++k) {
        float2 wv = W2v[k * 64 + lane];
        for (int r = 0; r < 4; ++r) {
            float a = sa[w * 4 + r][k];
            acc[r].x = fmaf(a, wv.x, acc[r].x);
            acc[r].y = fmaf(a, wv.y, acc[r].y);
        }
    }
    for (int r = 0; r < 4; ++r) {
        int row = row0 + r;
        if (row < N) Y[(size_t)row * 64 + lane] = acc[r];
    }
}

extern "C" void kernel_launch(void* const* d_in, const int* in_sizes, int n_in,
                              void* d_out, int out_size, void* d_ws, size_t ws_size,
                              hipStream_t stream) {
    const float* nf    = (const float*)d_in[0];
    const int*   ei    = (const int*)d_in[1];
    const float* W1    = (const float*)d_in[2];
    const float* b1    = (const float*)d_in[3];
    const float* gamma = (const float*)d_in[4];
    const float* beta  = (const float*)d_in[5];
    const float* W2    = (const float*)d_in[6];
    const float* b2    = (const float*)d_in[7];
    float* out = (float*)d_out;

    const int N = in_sizes[0] / CIN;      // 50000
    const int E = in_sizes[1] / 2;        // 800000
    const int* src = ei;
    const int* dst = ei + E;

    char* ws = (char*)d_ws;
    auto align256 = [](size_t x) { return (x + 255) & ~(size_t)255; };
    size_t off = 0;
    int*   degi = (int*)(ws + off);      off += align256((size_t)N * 4);
    float* dinv = (float*)(ws + off);    off += align256((size_t)N * 4);
    int*   rowstart = (int*)(ws + off);  off += align256((size_t)(N + 1) * 4);
    int*   cursor = (int*)(ws + off);    off += align256((size_t)N * 4);
    int*   blocksum = (int*)(ws + off);  off += align256(256 * 4);
    float* stats = (float*)(ws + off);   off += align256(512 * 4);
    float* scsh = (float*)(ws + off);    off += align256(512 * 4);
    int*   csr_src = (int*)(ws + off);   off += align256((size_t)E * 4);
    float* csr_w = (float*)(ws + off);   off += align256((size_t)E * 4);
    float* agg1 = (float*)(ws + off);    off += align256((size_t)N * CIN * 4);
    float* x1 = (float*)(ws + off);      off += align256((size_t)N * CH * 4);
    float* y = (float*)(ws + off);       off += align256((size_t)N * COUT * 4);

    int nbN = (N + 255) / 256;
    int nbE = (E + 255) / 256;

    // degree + norm
    k_init<<<nbN, 256, 0, stream>>>(degi, stats, N);
    k_deg<<<nbE, 256, 0, stream>>>(dst, degi, E);
    k_dinv<<<nbN, 256, 0, stream>>>(degi, dinv, N);

    // CSR build: 2-level exclusive scan + cursor fill
    k_scan1<<<nbN, 256, 0, stream>>>(degi, blocksum, N);
    k_scan2<<<1, 256, 0, stream>>>(blocksum, nbN, rowstart, N, E);
    k_scan3<<<nbN, 256, 0, stream>>>(degi, blocksum, rowstart, cursor, N);
    k_fill<<<nbE, 256, 0, stream>>>(src, dst, dinv, cursor, csr_src, csr_w, E);

    // layer 1 aggregation (gather): agg1 = S @ node_feat
    k_gather<<<(N * 32 + 255) / 256, 256, 0, stream>>>(
        (const float4*)nf, rowstart, csr_src, csr_w, dinv, nullptr, (float4*)agg1, N);

    // x1 = agg1 @ W1 + b1
    k_gemm1<<<(N + 15) / 16, 256, 0, stream>>>(
        agg1, (const float4*)W1, (const float4*)b1, (float4*)x1, N);

    // batch norm stats + scale/shift
    int nblk = 200;
    int rpb = (N + nblk - 1) / nblk;
    k_bnstats<<<nblk, 256, 0, stream>>>(x1, stats, N, rpb);
    k_bnfinal<<<1, 256, 0, stream>>>(stats, gamma, beta, scsh, N);

    // y = relu(bn(x1)) @ W2
    k_gemm2<<<(N + 15) / 16, 256, 0, stream>>>(
        (const float4*)x1, (const float4*)scsh, (const float4*)(scsh + 256),
        (const float2*)W2, (float2*)y, N);

    // out = S @ y + b2  (gather, bias fused)
    k_gather<<<(N * 32 + 255) / 256, 256, 0, stream>>>(
        (const float4*)y, rowstart, csr_src, csr_w, dinv, (const float4*)b2, (float4*)out, N);
}

// Round 3
// 512.174 us; speedup vs baseline: 5.9829x; 1.0346x over previous
//
#include <hip/hip_runtime.h>

#define CIN 128
#define CH 256
#define COUT 128
#define BN_EPS 1e-5f

typedef __attribute__((ext_vector_type(8))) short bf16x8;
typedef __attribute__((ext_vector_type(4))) float f32x4;

__device__ __forceinline__ void fma4(float4& a, float s, const float4& b) {
    a.x = fmaf(s, b.x, a.x);
    a.y = fmaf(s, b.y, a.y);
    a.z = fmaf(s, b.z, a.z);
    a.w = fmaf(s, b.w, a.w);
}

// float -> bf16 (round-to-nearest-even), raw short
__device__ __forceinline__ short f2bf(float x) {
    unsigned u = __float_as_uint(x);
    unsigned r = (u + 0x7fffu + ((u >> 16) & 1u)) >> 16;
    return (short)r;
}
__device__ __forceinline__ float bf2f(short h) {
    return __uint_as_float(((unsigned)(unsigned short)h) << 16);
}

// zero in-degree counters and BN stats accumulators
__global__ void k_init(int* __restrict__ degi, float* __restrict__ stats, int N) {
    int i = blockIdx.x * 256 + threadIdx.x;
    if (i < N) degi[i] = 0;
    if (i < 512) stats[i] = 0.0f;
}

__global__ void k_deg(const int* __restrict__ dst, int* __restrict__ degi, int E) {
    int e = blockIdx.x * 256 + threadIdx.x;
    if (e < E) atomicAdd(&degi[dst[e]], 1);
}

__global__ void k_dinv(const int* __restrict__ degi, float* __restrict__ dinv, int N) {
    int i = blockIdx.x * 256 + threadIdx.x;
    if (i < N) dinv[i] = rsqrtf((float)(degi[i] + 1));
}

__global__ void k_scan1(const int* __restrict__ degi, int* __restrict__ blocksum, int N) {
    __shared__ int s[256];
    int i = blockIdx.x * 256 + threadIdx.x;
    s[threadIdx.x] = (i < N) ? degi[i] : 0;
    __syncthreads();
    for (int st = 128; st > 0; st >>= 1) {
        if (threadIdx.x < st) s[threadIdx.x] += s[threadIdx.x + st];
        __syncthreads();
    }
    if (threadIdx.x == 0) blocksum[blockIdx.x] = s[0];
}

__global__ void k_scan2(int* __restrict__ blocksum, int nb,
                        int* __restrict__ rowstart, int N, int E) {
    __shared__ int s[256];
    int v = (threadIdx.x < nb) ? blocksum[threadIdx.x] : 0;
    s[threadIdx.x] = v;
    __syncthreads();
    for (int st = 1; st < 256; st <<= 1) {
        int t = (threadIdx.x >= st) ? s[threadIdx.x - st] : 0;
        __syncthreads();
        s[threadIdx.x] += t;
        __syncthreads();
    }
    if (threadIdx.x < nb) blocksum[threadIdx.x] = s[threadIdx.x] - v;
    if (threadIdx.x == 0) rowstart[N] = E;
}

__global__ void k_scan3(const int* __restrict__ degi, const int* __restrict__ blockoff,
                        int* __restrict__ rowstart, int* __restrict__ cursor, int N) {
    __shared__ int s[256];
    int i = blockIdx.x * 256 + threadIdx.x;
    int v = (i < N) ? degi[i] : 0;
    s[threadIdx.x] = v;
    __syncthreads();
    for (int st = 1; st < 256; st <<= 1) {
        int t = (threadIdx.x >= st) ? s[threadIdx.x - st] : 0;
        __syncthreads();
        s[threadIdx.x] += t;
        __syncthreads();
    }
    if (i < N) {
        int ex = s[threadIdx.x] - v + blockoff[blockIdx.x];
        rowstart[i] = ex;
        cursor[i] = ex;
    }
}

__global__ void k_fill(const int* __restrict__ src, const int* __restrict__ dst,
                       const float* __restrict__ dinv, int* __restrict__ cursor,
                       int* __restrict__ csr_src, float* __restrict__ csr_w, int E) {
    int e = blockIdx.x * 256 + threadIdx.x;
    if (e >= E) return;
    int s = src[e];
    int d = dst[e];
    int pos = atomicAdd(&cursor[d], 1);
    csr_src[pos] = s;
    csr_w[pos] = dinv[s] * dinv[d];
}

// transpose + bf16-split both weight matrices
__global__ void k_wprep(const float* __restrict__ W1, const float* __restrict__ W2,
                        short* __restrict__ W1Th, short* __restrict__ W1Tl,
                        short* __restrict__ W2Th, short* __restrict__ W2Tl) {
    int t = blockIdx.x * 256 + threadIdx.x;
    if (t < 32768) {                 // W1 [128][256] -> W1T [256][128]
        int n = t >> 7, k = t & 127;
        float v = W1[k * 256 + n];
        short h = f2bf(v);
        W1Th[t] = h;
        W1Tl[t] = f2bf(v - bf2f(h));
    } else {                         // W2 [256][128] -> W2T [128][256]
        int u = t - 32768;
        int n = u >> 8, k = u & 255;
        float v = W2[k * 128 + n];
        short h = f2bf(v);
        W2Th[u] = h;
        W2Tl[u] = f2bf(v - bf2f(h));
    }
}

// aggregation gather: acc = dinv[r]^2*x[r] + sum w_e x[src_e]
// MODE 0: write bf16 split (oh/ol); MODE 1: write fp32 + bias
template <int MODE>
__global__ __launch_bounds__(256) void k_gather(const float4* __restrict__ x,
                                                const int* __restrict__ rowstart,
                                                const int* __restrict__ csr_src,
                                                const float* __restrict__ csr_w,
                                                const float* __restrict__ dinv,
                                                const float4* __restrict__ bias4,
                                                float4* __restrict__ out,
                                                short* __restrict__ oh,
                                                short* __restrict__ ol, int N) {
    int t = blockIdx.x * 256 + threadIdx.x;
    int r = t >> 5;
    int c = t & 31;
    if (r >= N) return;
    float di = dinv[r];
    float w0 = di * di;
    float4 v = x[(size_t)r * 32 + c];
    float4 acc;
    acc.x = v.x * w0; acc.y = v.y * w0; acc.z = v.z * w0; acc.w = v.w * w0;
    int e0 = rowstart[r], e1 = rowstart[r + 1];
    int e = e0;
    for (; e + 1 < e1; e += 2) {
        int sA = csr_src[e];
        int sB = csr_src[e + 1];
        float wA = csr_w[e];
        float wB = csr_w[e + 1];
        float4 xa = x[(size_t)sA * 32 + c];
        float4 xb = x[(size_t)sB * 32 + c];
        fma4(acc, wA, xa);
        fma4(acc, wB, xb);
    }
    if (e < e1) {
        float4 xa = x[(size_t)csr_src[e] * 32 + c];
        fma4(acc, csr_w[e], xa);
    }
    if (MODE == 0) {
        short4 h, l;
        h.x = f2bf(acc.x); l.x = f2bf(acc.x - bf2f(h.x));
        h.y = f2bf(acc.y); l.y = f2bf(acc.y - bf2f(h.y));
        h.z = f2bf(acc.z); l.z = f2bf(acc.z - bf2f(h.z));
        h.w = f2bf(acc.w); l.w = f2bf(acc.w - bf2f(h.w));
        *(short4*)(oh + (size_t)r * 128 + c * 4) = h;
        *(short4*)(ol + (size_t)r * 128 + c * 4) = l;
    } else {
        float4 b = bias4[c];
        acc.x += b.x; acc.y += b.y; acc.z += b.z; acc.w += b.w;
        out[(size_t)r * 32 + c] = acc;
    }
}

// C[M,NOUT] = (Ah+Al)[M,K] @ (Bh+Bl)^T[NOUT,K] (+bias), split-bf16 3-term MFMA.
// Block = 4 waves; wave computes 16 rows x 64 cols (4 16x16 tiles), K in steps of 32.
__global__ __launch_bounds__(256) void k_gemm_mfma(const short* __restrict__ Ah,
                                                   const short* __restrict__ Al,
                                                   const short* __restrict__ Bh,
                                                   const short* __restrict__ Bl,
                                                   const float* __restrict__ bias,
                                                   float* __restrict__ C,
                                                   int M, int NOUT, int K) {
    int wave = threadIdx.x >> 6;
    int lane = threadIdx.x & 63;
    int m = lane & 15;
    int q = lane >> 4;
    int row0 = blockIdx.x * 64 + wave * 16;
    int col0 = blockIdx.y * 64;
    int arow = row0 + m;
    if (arow > M - 1) arow = M - 1;
    const short* pah = Ah + (size_t)arow * K + q * 8;
    const short* pal = Al + (size_t)arow * K + q * 8;

    f32x4 acc[4];
    #pragma unroll
    for (int n = 0; n < 4; ++n) acc[n] = (f32x4){0.f, 0.f, 0.f, 0.f};

    for (int k0 = 0; k0 < K; k0 += 32) {
        bf16x8 ah = *(const bf16x8*)(pah + k0);
        bf16x8 al = *(const bf16x8*)(pal + k0);
        #pragma unroll
        for (int n = 0; n < 4; ++n) {
            size_t boff = (size_t)(col0 + n * 16 + m) * K + q * 8 + k0;
            bf16x8 bh = *(const bf16x8*)(Bh + boff);
            bf16x8 bl = *(const bf16x8*)(Bl + boff);
            acc[n] = __builtin_amdgcn_mfma_f32_16x16x32_bf16(ah, bh, acc[n], 0, 0, 0);
            acc[n] = __builtin_amdgcn_mfma_f32_16x16x32_bf16(ah, bl, acc[n], 0, 0, 0);
            acc[n] = __builtin_amdgcn_mfma_f32_16x16x32_bf16(al, bh, acc[n], 0, 0, 0);
        }
    }
    #pragma unroll
    for (int n = 0; n < 4; ++n) {
        int col = col0 + n * 16 + m;
        float bv = bias ? bias[col] : 0.f;
        #pragma unroll
        for (int r = 0; r < 4; ++r) {
            int row = row0 + q * 4 + r;
            if (row < M) C[(size_t)row * NOUT + col] = acc[n][r] + bv;
        }
    }
}

// per-channel sum/sumsq of X1[N,256]
__global__ void k_bnstats(const float* __restrict__ X, float* __restrict__ stats,
                          int N, int rpb) {
    int c = threadIdx.x;
    int r0 = blockIdx.x * rpb;
    float s = 0.f, sq = 0.f;
    for (int i = 0; i < rpb; ++i) {
        int r = r0 + i;
        if (r < N) {
            float v = X[(size_t)r * 256 + c];
            s += v;
            sq = fmaf(v, v, sq);
        }
    }
    unsafeAtomicAdd(&stats[c], s);
    unsafeAtomicAdd(&stats[256 + c], sq);
}

__global__ void k_bnfinal(const float* __restrict__ stats, const float* __restrict__ gamma,
                          const float* __restrict__ beta, float* __restrict__ scsh, int N) {
    int c = threadIdx.x;
    float invN = 1.0f / (float)N;
    float mean = stats[c] * invN;
    float var = stats[256 + c] * invN - mean * mean;
    var = fmaxf(var, 0.f);
    float inv = rsqrtf(var + BN_EPS);
    float sc = gamma[c] * inv;
    scsh[c] = sc;
    scsh[256 + c] = fmaf(-mean, sc, beta[c]);
}

// z = relu(x1*sc+sh), split to bf16 hi/lo
__global__ void k_bnrelu(const float4* __restrict__ X4, const float* __restrict__ scsh,
                         short* __restrict__ Zh, short* __restrict__ Zl, int total) {
    int t = blockIdx.x * 256 + threadIdx.x;
    if (t >= total) return;
    int c = t & 63;
    float4 v = X4[t];
    float4 sc = *(const float4*)(scsh + c * 4);
    float4 sh = *(const float4*)(scsh + 256 + c * 4);
    float z0 = fmaxf(fmaf(v.x, sc.x, sh.x), 0.f);
    float z1 = fmaxf(fmaf(v.y, sc.y, sh.y), 0.f);
    float z2 = fmaxf(fmaf(v.z, sc.z, sh.z), 0.f);
    float z3 = fmaxf(fmaf(v.w, sc.w, sh.w), 0.f);
    short4 h, l;
    h.x = f2bf(z0); l.x = f2bf(z0 - bf2f(h.x));
    h.y = f2bf(z1); l.y = f2bf(z1 - bf2f(h.y));
    h.z = f2bf(z2); l.z = f2bf(z2 - bf2f(h.z));
    h.w = f2bf(z3); l.w = f2bf(z3 - bf2f(h.w));
    *(short4*)(Zh + (size_t)t * 4) = h;
    *(short4*)(Zl + (size_t)t * 4) = l;
}

extern "C" void kernel_launch(void* const* d_in, const int* in_sizes, int n_in,
                              void* d_out, int out_size, void* d_ws, size_t ws_size,
                              hipStream_t stream) {
    const float* nf    = (const float*)d_in[0];
    const int*   ei    = (const int*)d_in[1];
    const float* W1    = (const float*)d_in[2];
    const float* b1    = (const float*)d_in[3];
    const float* gamma = (const float*)d_in[4];
    const float* beta  = (const float*)d_in[5];
    const float* W2    = (const float*)d_in[6];
    const float* b2    = (const float*)d_in[7];
    float* out = (float*)d_out;

    const int N = in_sizes[0] / CIN;      // 50000
    const int E = in_sizes[1] / 2;        // 800000
    const int* src = ei;
    const int* dst = ei + E;

    char* ws = (char*)d_ws;
    auto align256 = [](size_t x) { return (x + 255) & ~(size_t)255; };
    size_t off = 0;
    int*   degi = (int*)(ws + off);      off += align256((size_t)N * 4);
    float* dinv = (float*)(ws + off);    off += align256((size_t)N * 4);
    int*   rowstart = (int*)(ws + off);  off += align256((size_t)(N + 1) * 4);
    int*   cursor = (int*)(ws + off);    off += align256((size_t)N * 4);
    int*   blocksum = (int*)(ws + off);  off += align256(256 * 4);
    float* stats = (float*)(ws + off);   off += align256(512 * 4);
    float* scsh = (float*)(ws + off);    off += align256(512 * 4);
    short* W1Th = (short*)(ws + off);    off += align256(32768 * 2);
    short* W1Tl = (short*)(ws + off);    off += align256(32768 * 2);
    short* W2Th = (short*)(ws + off);    off += align256(32768 * 2);
    short* W2Tl = (short*)(ws + off);    off += align256(32768 * 2);
    int*   csr_src = (int*)(ws + off);   off += align256((size_t)E * 4);
    float* csr_w = (float*)(ws + off);   off += align256((size_t)E * 4);
    short* agg1h = (short*)(ws + off);   off += align256((size_t)N * CIN * 2);  // aliased by y later
    short* agg1l = (short*)(ws + off);   off += align256((size_t)N * CIN * 2);
    float* x1 = (float*)(ws + off);      off += align256((size_t)N * CH * 4);
    short* zh = (short*)(ws + off);      off += align256((size_t)N * CH * 2);
    short* zl = (short*)(ws + off);      off += align256((size_t)N * CH * 2);
    float* y = (float*)agg1h;            // reuse agg1h+agg1l region (25.6 MB) after gemm1

    int nbN = (N + 255) / 256;
    int nbE = (E + 255) / 256;

    // degree + norm
    k_init<<<nbN, 256, 0, stream>>>(degi, stats, N);
    k_deg<<<nbE, 256, 0, stream>>>(dst, degi, E);
    k_dinv<<<nbN, 256, 0, stream>>>(degi, dinv, N);

    // CSR build
    k_scan1<<<nbN, 256, 0, stream>>>(degi, blocksum, N);
    k_scan2<<<1, 256, 0, stream>>>(blocksum, nbN, rowstart, N, E);
    k_scan3<<<nbN, 256, 0, stream>>>(degi, blocksum, rowstart, cursor, N);
    k_fill<<<nbE, 256, 0, stream>>>(src, dst, dinv, cursor, csr_src, csr_w, E);

    // weight transpose + split
    k_wprep<<<256, 256, 0, stream>>>(W1, W2, W1Th, W1Tl, W2Th, W2Tl);

    // layer 1 aggregation (gather) -> bf16 split
    k_gather<0><<<(N * 32 + 255) / 256, 256, 0, stream>>>(
        (const float4*)nf, rowstart, csr_src, csr_w, dinv, nullptr,
        nullptr, agg1h, agg1l, N);

    // x1 = agg1 @ W1 + b1   (MFMA split-bf16)
    {
        dim3 grid((N + 63) / 64, CH / 64);
        k_gemm_mfma<<<grid, 256, 0, stream>>>(agg1h, agg1l, W1Th, W1Tl, b1, x1,
                                              N, CH, CIN);
    }

    // batch norm
    int nblk = 200;
    int rpb = (N + nblk - 1) / nblk;
    k_bnstats<<<nblk, 256, 0, stream>>>(x1, stats, N, rpb);
    k_bnfinal<<<1, 256, 0, stream>>>(stats, gamma, beta, scsh, N);

    // z = relu(bn(x1)) -> bf16 split
    k_bnrelu<<<(N * 64 + 255) / 256, 256, 0, stream>>>(
        (const float4*)x1, scsh, zh, zl, N * 64);

    // y = z @ W2   (MFMA split-bf16, bias deferred to gather)
    {
        dim3 grid((N + 63) / 64, COUT / 64);
        k_gemm_mfma<<<grid, 256, 0, stream>>>(zh, zl, W2Th, W2Tl, nullptr, y,
                                              N, COUT, CH);
    }

    // out = S @ y + b2  (gather, fp32)
    k_gather<1><<<(N * 32 + 255) / 256, 256, 0, stream>>>(
        (const float4*)y, rowstart, csr_src, csr_w, dinv, (const float4*)b2,
        (float4*)out, nullptr, nullptr, N);
}

// Round 4
// 358.049 us; speedup vs baseline: 8.5583x; 1.4305x over previous
//
#include <hip/hip_runtime.h>

#define CIN 128
#define CH 256
#define COUT 128
#define BN_EPS 1e-5f

typedef __attribute__((ext_vector_type(8))) short bf16x8;
typedef __attribute__((ext_vector_type(4))) float f32x4;

// float -> bf16 (round-to-nearest-even), raw short
__device__ __forceinline__ short f2bf(float x) {
    unsigned u = __float_as_uint(x);
    unsigned r = (u + 0x7fffu + ((u >> 16) & 1u)) >> 16;
    return (short)r;
}
__device__ __forceinline__ float bf2f(short h) {
    return __uint_as_float(((unsigned)(unsigned short)h) << 16);
}

// zero in-degree counters and BN stats accumulators
__global__ void k_init(int* __restrict__ degi, float* __restrict__ stats, int N) {
    int i = blockIdx.x * 256 + threadIdx.x;
    if (i < N) degi[i] = 0;
    if (i < 512) stats[i] = 0.0f;
}

__global__ void k_deg(const int* __restrict__ dst, int* __restrict__ degi, int E) {
    int e = blockIdx.x * 256 + threadIdx.x;
    if (e < E) atomicAdd(&degi[dst[e]], 1);
}

__global__ void k_dinv(const int* __restrict__ degi, float* __restrict__ dinv, int N) {
    int i = blockIdx.x * 256 + threadIdx.x;
    if (i < N) dinv[i] = rsqrtf((float)(degi[i] + 1));
}

__global__ void k_scan1(const int* __restrict__ degi, int* __restrict__ blocksum, int N) {
    __shared__ int s[256];
    int i = blockIdx.x * 256 + threadIdx.x;
    s[threadIdx.x] = (i < N) ? degi[i] : 0;
    __syncthreads();
    for (int st = 128; st > 0; st >>= 1) {
        if (threadIdx.x < st) s[threadIdx.x] += s[threadIdx.x + st];
        __syncthreads();
    }
    if (threadIdx.x == 0) blocksum[blockIdx.x] = s[0];
}

__global__ void k_scan2(int* __restrict__ blocksum, int nb,
                        int* __restrict__ rowstart, int N, int E) {
    __shared__ int s[256];
    int v = (threadIdx.x < nb) ? blocksum[threadIdx.x] : 0;
    s[threadIdx.x] = v;
    __syncthreads();
    for (int st = 1; st < 256; st <<= 1) {
        int t = (threadIdx.x >= st) ? s[threadIdx.x - st] : 0;
        __syncthreads();
        s[threadIdx.x] += t;
        __syncthreads();
    }
    if (threadIdx.x < nb) blocksum[threadIdx.x] = s[threadIdx.x] - v;
    if (threadIdx.x == 0) rowstart[N] = E;
}

__global__ void k_scan3(const int* __restrict__ degi, const int* __restrict__ blockoff,
                        int* __restrict__ rowstart, int* __restrict__ cursor, int N) {
    __shared__ int s[256];
    int i = blockIdx.x * 256 + threadIdx.x;
    int v = (i < N) ? degi[i] : 0;
    s[threadIdx.x] = v;
    __syncthreads();
    for (int st = 1; st < 256; st <<= 1) {
        int t = (threadIdx.x >= st) ? s[threadIdx.x - st] : 0;
        __syncthreads();
        s[threadIdx.x] += t;
        __syncthreads();
    }
    if (i < N) {
        int ex = s[threadIdx.x] - v + blockoff[blockIdx.x];
        rowstart[i] = ex;
        cursor[i] = ex;
    }
}

__global__ void k_fill(const int* __restrict__ src, const int* __restrict__ dst,
                       const float* __restrict__ dinv, int* __restrict__ cursor,
                       int* __restrict__ csr_src, float* __restrict__ csr_w, int E) {
    int e = blockIdx.x * 256 + threadIdx.x;
    if (e >= E) return;
    int s = src[e];
    int d = dst[e];
    int pos = atomicAdd(&cursor[d], 1);
    csr_src[pos] = s;
    csr_w[pos] = dinv[s] * dinv[d];
}

// transpose + bf16-split both weight matrices
__global__ void k_wprep(const float* __restrict__ W1, const float* __restrict__ W2,
                        short* __restrict__ W1Th, short* __restrict__ W1Tl,
                        short* __restrict__ W2Th, short* __restrict__ W2Tl) {
    int t = blockIdx.x * 256 + threadIdx.x;
    if (t < 32768) {                 // W1 [128][256] -> W1T [256][128]
        int n = t >> 7, k = t & 127;
        float v = W1[k * 256 + n];
        short h = f2bf(v);
        W1Th[t] = h;
        W1Tl[t] = f2bf(v - bf2f(h));
    } else {                         // W2 [256][128] -> W2T [128][256]
        int u = t - 32768;
        int n = u >> 8, k = u & 255;
        float v = W2[k * 128 + n];
        short h = f2bf(v);
        W2Th[u] = h;
        W2Tl[u] = f2bf(v - bf2f(h));
    }
}

// fp32 -> bf16 cast, 4 elems/thread
__global__ void k_tobf(const float4* __restrict__ x, short4* __restrict__ o, int n4) {
    int t = blockIdx.x * 256 + threadIdx.x;
    if (t >= n4) return;
    float4 v = x[t];
    short4 s;
    s.x = f2bf(v.x); s.y = f2bf(v.y); s.z = f2bf(v.z); s.w = f2bf(v.w);
    o[t] = s;
}

// gather over CSR, bf16 input rows [N,128], fp32 accumulate.
// MODE 0: write bf16 row; MODE 1: write fp32 + bias (final output)
template <int MODE>
__global__ __launch_bounds__(256) void k_gather(const short* __restrict__ xb,
                                                const int* __restrict__ rowstart,
                                                const int* __restrict__ csr_src,
                                                const float* __restrict__ csr_w,
                                                const float* __restrict__ dinv,
                                                const float4* __restrict__ bias4,
                                                float4* __restrict__ out,
                                                short* __restrict__ ob, int N) {
    int t = blockIdx.x * 256 + threadIdx.x;
    int r = t >> 5;
    int c = t & 31;
    if (r >= N) return;
    float di = dinv[r];
    float w0 = di * di;
    short4 sv = *(const short4*)(xb + (size_t)r * 128 + c * 4);
    float4 acc;
    acc.x = bf2f(sv.x) * w0;
    acc.y = bf2f(sv.y) * w0;
    acc.z = bf2f(sv.z) * w0;
    acc.w = bf2f(sv.w) * w0;
    int e0 = rowstart[r], e1 = rowstart[r + 1];
    int e = e0;
    for (; e + 1 < e1; e += 2) {
        int sA = csr_src[e];
        int sB = csr_src[e + 1];
        float wA = csr_w[e];
        float wB = csr_w[e + 1];
        short4 xa = *(const short4*)(xb + (size_t)sA * 128 + c * 4);
        short4 xc = *(const short4*)(xb + (size_t)sB * 128 + c * 4);
        acc.x = fmaf(wA, bf2f(xa.x), acc.x); acc.x = fmaf(wB, bf2f(xc.x), acc.x);
        acc.y = fmaf(wA, bf2f(xa.y), acc.y); acc.y = fmaf(wB, bf2f(xc.y), acc.y);
        acc.z = fmaf(wA, bf2f(xa.z), acc.z); acc.z = fmaf(wB, bf2f(xc.z), acc.z);
        acc.w = fmaf(wA, bf2f(xa.w), acc.w); acc.w = fmaf(wB, bf2f(xc.w), acc.w);
    }
    if (e < e1) {
        int sA = csr_src[e];
        float wA = csr_w[e];
        short4 xa = *(const short4*)(xb + (size_t)sA * 128 + c * 4);
        acc.x = fmaf(wA, bf2f(xa.x), acc.x);
        acc.y = fmaf(wA, bf2f(xa.y), acc.y);
        acc.z = fmaf(wA, bf2f(xa.z), acc.z);
        acc.w = fmaf(wA, bf2f(xa.w), acc.w);
    }
    if (MODE == 0) {
        short4 h;
        h.x = f2bf(acc.x); h.y = f2bf(acc.y); h.z = f2bf(acc.z); h.w = f2bf(acc.w);
        *(short4*)(ob + (size_t)r * 128 + c * 4) = h;
    } else {
        float4 b = bias4[c];
        acc.x += b.x; acc.y += b.y; acc.z += b.z; acc.w += b.w;
        out[(size_t)r * 32 + c] = acc;
    }
}

// C[M,NOUT](bf16) = A[M,K](bf16) @ (Bh+Bl)^T[NOUT,K] + bias, optional fused BN stats.
// Block: 256 thr = 4 waves, 64 rows x full NOUT. Wave: 64 rows x NOUT/4 cols.
template <int K, int NOUT, bool STATS, bool BIAS>
__global__ __launch_bounds__(256) void k_gemm(const short* __restrict__ A,
                                              const short* __restrict__ Bh,
                                              const short* __restrict__ Bl,
                                              const float* __restrict__ bias,
                                              short* __restrict__ C,
                                              float* __restrict__ stats, int M) {
    constexpr int CT = NOUT / 64;   // col-tiles per wave
    constexpr int KS = K / 32;      // k-steps
    int wave = threadIdx.x >> 6;
    int lane = threadIdx.x & 63;
    int m = lane & 15;
    int q = lane >> 4;
    int row0 = blockIdx.x * 64;
    int colw = wave * (NOUT / 4);

    f32x4 acc[4][CT];
    #pragma unroll
    for (int rt = 0; rt < 4; ++rt)
        #pragma unroll
        for (int ct = 0; ct < CT; ++ct)
            acc[rt][ct] = (f32x4){0.f, 0.f, 0.f, 0.f};

    const short* pa[4];
    #pragma unroll
    for (int rt = 0; rt < 4; ++rt) {
        int ar = row0 + rt * 16 + m;
        if (ar >= M) ar = M - 1;
        pa[rt] = A + (size_t)ar * K + q * 8;
    }

    #pragma unroll
    for (int ks = 0; ks < KS; ++ks) {
        bf16x8 af[4];
        #pragma unroll
        for (int rt = 0; rt < 4; ++rt) af[rt] = *(const bf16x8*)(pa[rt] + ks * 32);
        #pragma unroll
        for (int ct = 0; ct < CT; ++ct) {
            size_t bo = (size_t)(colw + ct * 16 + m) * K + ks * 32 + q * 8;
            bf16x8 bh = *(const bf16x8*)(Bh + bo);
            bf16x8 bl = *(const bf16x8*)(Bl + bo);
            #pragma unroll
            for (int rt = 0; rt < 4; ++rt) {
                acc[rt][ct] = __builtin_amdgcn_mfma_f32_16x16x32_bf16(af[rt], bh, acc[rt][ct], 0, 0, 0);
                acc[rt][ct] = __builtin_amdgcn_mfma_f32_16x16x32_bf16(af[rt], bl, acc[rt][ct], 0, 0, 0);
            }
        }
    }

    #pragma unroll
    for (int ct = 0; ct < CT; ++ct) {
        int col = colw + ct * 16 + m;
        float bv = BIAS ? bias[col] : 0.f;
        float s = 0.f, sq = 0.f;
        #pragma unroll
        for (int rt = 0; rt < 4; ++rt) {
            #pragma unroll
            for (int r = 0; r < 4; ++r) {
                int row = row0 + rt * 16 + q * 4 + r;
                if (row < M) {
                    float v = acc[rt][ct][r] + bv;
                    if (STATS) { s += v; sq = fmaf(v, v, sq); }
                    C[(size_t)row * NOUT + col] = f2bf(v);
                }
            }
        }
        if (STATS) {
            s += __shfl_xor(s, 16, 64);
            s += __shfl_xor(s, 32, 64);
            sq += __shfl_xor(sq, 16, 64);
            sq += __shfl_xor(sq, 32, 64);
            if (lane < 16) {
                unsafeAtomicAdd(&stats[col], s);
                unsafeAtomicAdd(&stats[256 + col], sq);
            }
        }
    }
}

__global__ void k_bnfinal(const float* __restrict__ stats, const float* __restrict__ gamma,
                          const float* __restrict__ beta, float* __restrict__ scsh, int N) {
    int c = threadIdx.x;
    float invN = 1.0f / (float)N;
    float mean = stats[c] * invN;
    float var = stats[256 + c] * invN - mean * mean;
    var = fmaxf(var, 0.f);
    float inv = rsqrtf(var + BN_EPS);
    float sc = gamma[c] * inv;
    scsh[c] = sc;
    scsh[256 + c] = fmaf(-mean, sc, beta[c]);
}

// z = relu(x1*sc+sh), bf16 in/out, 8 elems/thread
__global__ void k_bnrelu(const short* __restrict__ X, const float* __restrict__ scsh,
                         short* __restrict__ Z, int total8) {
    int t = blockIdx.x * 256 + threadIdx.x;
    if (t >= total8) return;
    int c = (t & 31) * 8;
    short4 a = *(const short4*)(X + (size_t)t * 8);
    short4 b = *(const short4*)(X + (size_t)t * 8 + 4);
    float4 sc0 = *(const float4*)(scsh + c);
    float4 sc1 = *(const float4*)(scsh + c + 4);
    float4 sh0 = *(const float4*)(scsh + 256 + c);
    float4 sh1 = *(const float4*)(scsh + 256 + c + 4);
    short4 o0, o1;
    o0.x = f2bf(fmaxf(fmaf(bf2f(a.x), sc0.x, sh0.x), 0.f));
    o0.y = f2bf(fmaxf(fmaf(bf2f(a.y), sc0.y, sh0.y), 0.f));
    o0.z = f2bf(fmaxf(fmaf(bf2f(a.z), sc0.z, sh0.z), 0.f));
    o0.w = f2bf(fmaxf(fmaf(bf2f(a.w), sc0.w, sh0.w), 0.f));
    o1.x = f2bf(fmaxf(fmaf(bf2f(b.x), sc1.x, sh1.x), 0.f));
    o1.y = f2bf(fmaxf(fmaf(bf2f(b.y), sc1.y, sh1.y), 0.f));
    o1.z = f2bf(fmaxf(fmaf(bf2f(b.z), sc1.z, sh1.z), 0.f));
    o1.w = f2bf(fmaxf(fmaf(bf2f(b.w), sc1.w, sh1.w), 0.f));
    *(short4*)(Z + (size_t)t * 8) = o0;
    *(short4*)(Z + (size_t)t * 8 + 4) = o1;
}

extern "C" void kernel_launch(void* const* d_in, const int* in_sizes, int n_in,
                              void* d_out, int out_size, void* d_ws, size_t ws_size,
                              hipStream_t stream) {
    const float* nf    = (const float*)d_in[0];
    const int*   ei    = (const int*)d_in[1];
    const float* W1    = (const float*)d_in[2];
    const float* b1    = (const float*)d_in[3];
    const float* gamma = (const float*)d_in[4];
    const float* beta  = (const float*)d_in[5];
    const float* W2    = (const float*)d_in[6];
    const float* b2    = (const float*)d_in[7];
    float* out = (float*)d_out;

    const int N = in_sizes[0] / CIN;      // 50000
    const int E = in_sizes[1] / 2;        // 800000
    const int* src = ei;
    const int* dst = ei + E;

    char* ws = (char*)d_ws;
    auto align256 = [](size_t x) { return (x + 255) & ~(size_t)255; };
    size_t off = 0;
    int*   degi = (int*)(ws + off);      off += align256((size_t)N * 4);
    float* dinv = (float*)(ws + off);    off += align256((size_t)N * 4);
    int*   rowstart = (int*)(ws + off);  off += align256((size_t)(N + 1) * 4);
    int*   cursor = (int*)(ws + off);    off += align256((size_t)N * 4);
    int*   blocksum = (int*)(ws + off);  off += align256(256 * 4);
    float* stats = (float*)(ws + off);   off += align256(512 * 4);
    float* scsh = (float*)(ws + off);    off += align256(512 * 4);
    short* W1Th = (short*)(ws + off);    off += align256(32768 * 2);
    short* W1Tl = (short*)(ws + off);    off += align256(32768 * 2);
    short* W2Th = (short*)(ws + off);    off += align256(32768 * 2);
    short* W2Tl = (short*)(ws + off);    off += align256(32768 * 2);
    int*   csr_src = (int*)(ws + off);   off += align256((size_t)E * 4);
    float* csr_w = (float*)(ws + off);   off += align256((size_t)E * 4);
    short* nfb = (short*)(ws + off);     off += align256((size_t)N * CIN * 2);   // nf bf16
    short* agg1b = (short*)(ws + off);   off += align256((size_t)N * CIN * 2);   // S@x bf16
    short* x1b = (short*)(ws + off);     off += align256((size_t)N * CH * 2);    // layer1 bf16
    short* zb = (short*)(ws + off);      off += align256((size_t)N * CH * 2);    // relu(bn) bf16
    short* yb = (short*)(ws + off);      off += align256((size_t)N * COUT * 2);  // z@W2 bf16

    int nbN = (N + 255) / 256;
    int nbE = (E + 255) / 256;

    // degree + norm
    k_init<<<nbN, 256, 0, stream>>>(degi, stats, N);
    k_deg<<<nbE, 256, 0, stream>>>(dst, degi, E);
    k_dinv<<<nbN, 256, 0, stream>>>(degi, dinv, N);

    // CSR build
    k_scan1<<<nbN, 256, 0, stream>>>(degi, blocksum, N);
    k_scan2<<<1, 256, 0, stream>>>(blocksum, nbN, rowstart, N, E);
    k_scan3<<<nbN, 256, 0, stream>>>(degi, blocksum, rowstart, cursor, N);
    k_fill<<<nbE, 256, 0, stream>>>(src, dst, dinv, cursor, csr_src, csr_w, E);

    // weight transpose + split; node features -> bf16
    k_wprep<<<256, 256, 0, stream>>>(W1, W2, W1Th, W1Tl, W2Th, W2Tl);
    k_tobf<<<(N * 32 + 255) / 256, 256, 0, stream>>>((const float4*)nf, (short4*)nfb, N * 32);

    // layer 1 aggregation (gather, bf16 in/out)
    k_gather<0><<<(N * 32 + 255) / 256, 256, 0, stream>>>(
        nfb, rowstart, csr_src, csr_w, dinv, nullptr, nullptr, agg1b, N);

    // x1 = agg1 @ W1 + b1, fused BN stats
    k_gemm<CIN, CH, true, true><<<(N + 63) / 64, 256, 0, stream>>>(
        agg1b, W1Th, W1Tl, b1, x1b, stats, N);

    // BN scale/shift
    k_bnfinal<<<1, 256, 0, stream>>>(stats, gamma, beta, scsh, N);

    // z = relu(bn(x1)), bf16
    k_bnrelu<<<(N * 32 + 255) / 256, 256, 0, stream>>>(x1b, scsh, zb, N * 32);

    // y = z @ W2 (bias deferred to gather)
    k_gemm<CH, COUT, false, false><<<(N + 63) / 64, 256, 0, stream>>>(
        zb, W2Th, W2Tl, nullptr, yb, nullptr, N);

    // out = S @ y + b2
    k_gather<1><<<(N * 32 + 255) / 256, 256, 0, stream>>>(
        yb, rowstart, csr_src, csr_w, dinv, (const float4*)b2, (float4*)out, nullptr, N);
}

// Round 5
// 339.210 us; speedup vs baseline: 9.0336x; 1.0555x over previous
//
#include <hip/hip_runtime.h>

#define CIN 128
#define CH 256
#define COUT 128
#define BN_EPS 1e-5f

typedef __attribute__((ext_vector_type(8))) short bf16x8;
typedef __attribute__((ext_vector_type(4))) float f32x4;

// float -> bf16 (round-to-nearest-even), raw short
__device__ __forceinline__ short f2bf(float x) {
    unsigned u = __float_as_uint(x);
    unsigned r = (u + 0x7fffu + ((u >> 16) & 1u)) >> 16;
    return (short)r;
}
__device__ __forceinline__ float bf2f(short h) {
    return __uint_as_float(((unsigned)(unsigned short)h) << 16);
}

__global__ void k_init(int* __restrict__ degi, float* __restrict__ stats, int N) {
    int i = blockIdx.x * 256 + threadIdx.x;
    if (i < N) degi[i] = 0;
    if (i < 512) stats[i] = 0.0f;
}

__global__ void k_deg(const int* __restrict__ dst, int* __restrict__ degi, int E) {
    int e = blockIdx.x * 256 + threadIdx.x;
    if (e < E) atomicAdd(&degi[dst[e]], 1);
}

__global__ void k_dinv(const int* __restrict__ degi, float* __restrict__ dinv, int N) {
    int i = blockIdx.x * 256 + threadIdx.x;
    if (i < N) dinv[i] = rsqrtf((float)(degi[i] + 1));
}

__global__ void k_scan1(const int* __restrict__ degi, int* __restrict__ blocksum, int N) {
    __shared__ int s[256];
    int i = blockIdx.x * 256 + threadIdx.x;
    s[threadIdx.x] = (i < N) ? degi[i] : 0;
    __syncthreads();
    for (int st = 128; st > 0; st >>= 1) {
        if (threadIdx.x < st) s[threadIdx.x] += s[threadIdx.x + st];
        __syncthreads();
    }
    if (threadIdx.x == 0) blocksum[blockIdx.x] = s[0];
}

__global__ void k_scan2(int* __restrict__ blocksum, int nb,
                        int* __restrict__ rowstart, int N, int E) {
    __shared__ int s[256];
    int v = (threadIdx.x < nb) ? blocksum[threadIdx.x] : 0;
    s[threadIdx.x] = v;
    __syncthreads();
    for (int st = 1; st < 256; st <<= 1) {
        int t = (threadIdx.x >= st) ? s[threadIdx.x - st] : 0;
        __syncthreads();
        s[threadIdx.x] += t;
        __syncthreads();
    }
    if (threadIdx.x < nb) blocksum[threadIdx.x] = s[threadIdx.x] - v;
    if (threadIdx.x == 0) rowstart[N] = E;
}

__global__ void k_scan3(const int* __restrict__ degi, const int* __restrict__ blockoff,
                        int* __restrict__ rowstart, int* __restrict__ cursor, int N) {
    __shared__ int s[256];
    int i = blockIdx.x * 256 + threadIdx.x;
    int v = (i < N) ? degi[i] : 0;
    s[threadIdx.x] = v;
    __syncthreads();
    for (int st = 1; st < 256; st <<= 1) {
        int t = (threadIdx.x >= st) ? s[threadIdx.x - st] : 0;
        __syncthreads();
        s[threadIdx.x] += t;
        __syncthreads();
    }
    if (i < N) {
        int ex = s[threadIdx.x] - v + blockoff[blockIdx.x];
        rowstart[i] = ex;
        cursor[i] = ex;
    }
}

__global__ void k_fill(const int* __restrict__ src, const int* __restrict__ dst,
                       const float* __restrict__ dinv, int* __restrict__ cursor,
                       int* __restrict__ csr_src, float* __restrict__ csr_w, int E) {
    int e = blockIdx.x * 256 + threadIdx.x;
    if (e >= E) return;
    int s = src[e];
    int d = dst[e];
    int pos = atomicAdd(&cursor[d], 1);
    csr_src[pos] = s;
    csr_w[pos] = dinv[s] * dinv[d];
}

// transpose + bf16-split both weight matrices
__global__ void k_wprep(const float* __restrict__ W1, const float* __restrict__ W2,
                        short* __restrict__ W1Th, short* __restrict__ W1Tl,
                        short* __restrict__ W2Th, short* __restrict__ W2Tl) {
    int t = blockIdx.x * 256 + threadIdx.x;
    if (t < 32768) {                 // W1 [128][256] -> W1T [256][128]
        int n = t >> 7, k = t & 127;
        float v = W1[k * 256 + n];
        short h = f2bf(v);
        W1Th[t] = h;
        W1Tl[t] = f2bf(v - bf2f(h));
    } else {                         // W2 [256][128] -> W2T [128][256]
        int u = t - 32768;
        int n = u >> 8, k = u & 255;
        float v = W2[k * 128 + n];
        short h = f2bf(v);
        W2Th[u] = h;
        W2Tl[u] = f2bf(v - bf2f(h));
    }
}

// fp32 -> bf16 cast, 4 elems/thread
__global__ void k_tobf(const float4* __restrict__ x, short4* __restrict__ o, int n4) {
    int t = blockIdx.x * 256 + threadIdx.x;
    if (t >= n4) return;
    float4 v = x[t];
    short4 s;
    s.x = f2bf(v.x); s.y = f2bf(v.y); s.z = f2bf(v.z); s.w = f2bf(v.w);
    o[t] = s;
}

__device__ __forceinline__ void acc4(float4& acc, float w, short4 x) {
    acc.x = fmaf(w, bf2f(x.x), acc.x);
    acc.y = fmaf(w, bf2f(x.y), acc.y);
    acc.z = fmaf(w, bf2f(x.z), acc.z);
    acc.w = fmaf(w, bf2f(x.w), acc.w);
}

// gather over CSR, bf16 input rows [N,128], fp32 accumulate.
// MODE 0: write bf16 row; MODE 1: write fp32 + bias (final output)
template <int MODE>
__global__ __launch_bounds__(256) void k_gather(const short* __restrict__ xb,
                                                const int* __restrict__ rowstart,
                                                const int* __restrict__ csr_src,
                                                const float* __restrict__ csr_w,
                                                const float* __restrict__ dinv,
                                                const float4* __restrict__ bias4,
                                                float4* __restrict__ out,
                                                short* __restrict__ ob, int N) {
    int t = blockIdx.x * 256 + threadIdx.x;
    int r = t >> 5;
    int c = t & 31;
    if (r >= N) return;
    float di = dinv[r];
    float w0 = di * di;
    short4 sv = *(const short4*)(xb + (size_t)r * 128 + c * 4);
    float4 acc;
    acc.x = bf2f(sv.x) * w0;
    acc.y = bf2f(sv.y) * w0;
    acc.z = bf2f(sv.z) * w0;
    acc.w = bf2f(sv.w) * w0;
    int e0 = rowstart[r], e1 = rowstart[r + 1];
    int e = e0;
    for (; e + 3 < e1; e += 4) {
        int s0 = csr_src[e], s1 = csr_src[e + 1], s2 = csr_src[e + 2], s3 = csr_src[e + 3];
        float w0_ = csr_w[e], w1_ = csr_w[e + 1], w2_ = csr_w[e + 2], w3_ = csr_w[e + 3];
        short4 x0 = *(const short4*)(xb + (size_t)s0 * 128 + c * 4);
        short4 x1 = *(const short4*)(xb + (size_t)s1 * 128 + c * 4);
        short4 x2 = *(const short4*)(xb + (size_t)s2 * 128 + c * 4);
        short4 x3 = *(const short4*)(xb + (size_t)s3 * 128 + c * 4);
        acc4(acc, w0_, x0);
        acc4(acc, w1_, x1);
        acc4(acc, w2_, x2);
        acc4(acc, w3_, x3);
    }
    for (; e < e1; ++e) {
        int s0 = csr_src[e];
        float ww = csr_w[e];
        short4 x0 = *(const short4*)(xb + (size_t)s0 * 128 + c * 4);
        acc4(acc, ww, x0);
    }
    if (MODE == 0) {
        short4 h;
        h.x = f2bf(acc.x); h.y = f2bf(acc.y); h.z = f2bf(acc.z); h.w = f2bf(acc.w);
        *(short4*)(ob + (size_t)r * 128 + c * 4) = h;
    } else {
        float4 b = bias4[c];
        acc.x += b.x; acc.y += b.y; acc.z += b.z; acc.w += b.w;
        out[(size_t)r * 32 + c] = acc;
    }
}

__device__ __forceinline__ bf16x8 bnrelu8(bf16x8 raw, const float* __restrict__ scsh, int c) {
    float4 sc0 = *(const float4*)(scsh + c);
    float4 sc1 = *(const float4*)(scsh + c + 4);
    float4 sh0 = *(const float4*)(scsh + 256 + c);
    float4 sh1 = *(const float4*)(scsh + 256 + c + 4);
    bf16x8 o;
    o[0] = f2bf(fmaxf(fmaf(bf2f(raw[0]), sc0.x, sh0.x), 0.f));
    o[1] = f2bf(fmaxf(fmaf(bf2f(raw[1]), sc0.y, sh0.y), 0.f));
    o[2] = f2bf(fmaxf(fmaf(bf2f(raw[2]), sc0.z, sh0.z), 0.f));
    o[3] = f2bf(fmaxf(fmaf(bf2f(raw[3]), sc0.w, sh0.w), 0.f));
    o[4] = f2bf(fmaxf(fmaf(bf2f(raw[4]), sc1.x, sh1.x), 0.f));
    o[5] = f2bf(fmaxf(fmaf(bf2f(raw[5]), sc1.y, sh1.y), 0.f));
    o[6] = f2bf(fmaxf(fmaf(bf2f(raw[6]), sc1.z, sh1.z), 0.f));
    o[7] = f2bf(fmaxf(fmaf(bf2f(raw[7]), sc1.w, sh1.w), 0.f));
    return o;
}

// C[M,NOUT](bf16) = f(A)[M,K](bf16) @ (Bh+Bl)^T[NOUT,K] + bias
// f = identity or BN+ReLU (scsh). Optional fused BN stats on output.
// Block: 256 thr = 4 waves, 64 rows x full NOUT. Wave: 64 rows x NOUT/4 cols.
// B-fragments preloaded to registers (128 VGPRs); epilogue staged via LDS for
// coalesced 16B row writes (fixes partial-sector write amplification).
template <int K, int NOUT, bool STATS, bool BIAS, bool BNRELU>
__global__ __launch_bounds__(256, 2) void k_gemm(const short* __restrict__ A,
                                                 const short* __restrict__ Bh,
                                                 const short* __restrict__ Bl,
                                                 const float* __restrict__ bias,
                                                 const float* __restrict__ scsh,
                                                 short* __restrict__ C,
                                                 float* __restrict__ stats, int M) {
    constexpr int CT = NOUT / 64;   // col-tiles per wave
    constexpr int KS = K / 32;      // k-steps
    constexpr int LROW = NOUT + 8;  // padded LDS row (shorts)
    __shared__ short lds[64 * LROW];
    int wave = threadIdx.x >> 6;
    int lane = threadIdx.x & 63;
    int m = lane & 15;
    int q = lane >> 4;
    int row0 = blockIdx.x * 64;
    int colw = wave * (NOUT / 4);

    // preload all B fragments for this wave into registers
    bf16x8 bhf[CT][KS], blf[CT][KS];
    #pragma unroll
    for (int ct = 0; ct < CT; ++ct) {
        #pragma unroll
        for (int ks = 0; ks < KS; ++ks) {
            size_t bo = (size_t)(colw + ct * 16 + m) * K + ks * 32 + q * 8;
            bhf[ct][ks] = *(const bf16x8*)(Bh + bo);
            blf[ct][ks] = *(const bf16x8*)(Bl + bo);
        }
    }

    const short* pa[4];
    #pragma unroll
    for (int rt = 0; rt < 4; ++rt) {
        int ar = row0 + rt * 16 + m;
        if (ar >= M) ar = M - 1;
        pa[rt] = A + (size_t)ar * K + q * 8;
    }

    f32x4 acc[4][CT];
    #pragma unroll
    for (int rt = 0; rt < 4; ++rt)
        #pragma unroll
        for (int ct = 0; ct < CT; ++ct)
            acc[rt][ct] = (f32x4){0.f, 0.f, 0.f, 0.f};

    #pragma unroll
    for (int ks = 0; ks < KS; ++ks) {
        bf16x8 af[4];
        #pragma unroll
        for (int rt = 0; rt < 4; ++rt) {
            bf16x8 raw = *(const bf16x8*)(pa[rt] + ks * 32);
            af[rt] = BNRELU ? bnrelu8(raw, scsh, ks * 32 + q * 8) : raw;
        }
        #pragma unroll
        for (int ct = 0; ct < CT; ++ct) {
            #pragma unroll
            for (int rt = 0; rt < 4; ++rt) {
                acc[rt][ct] = __builtin_amdgcn_mfma_f32_16x16x32_bf16(af[rt], bhf[ct][ks], acc[rt][ct], 0, 0, 0);
                acc[rt][ct] = __builtin_amdgcn_mfma_f32_16x16x32_bf16(af[rt], blf[ct][ks], acc[rt][ct], 0, 0, 0);
            }
        }
    }

    // epilogue: bias (+stats), bf16 -> LDS, then coalesced global writes
    #pragma unroll
    for (int ct = 0; ct < CT; ++ct) {
        int col = colw + ct * 16 + m;
        float bv = BIAS ? bias[col] : 0.f;
        float s = 0.f, sq = 0.f;
        #pragma unroll
        for (int rt = 0; rt < 4; ++rt) {
            #pragma unroll
            for (int r = 0; r < 4; ++r) {
                int lrow = rt * 16 + q * 4 + r;
                float v = acc[rt][ct][r] + bv;
                if (STATS && row0 + lrow < M) { s += v; sq = fmaf(v, v, sq); }
                lds[lrow * LROW + col] = f2bf(v);
            }
        }
        if (STATS) {
            s += __shfl_xor(s, 16, 64);
            s += __shfl_xor(s, 32, 64);
            sq += __shfl_xor(sq, 16, 64);
            sq += __shfl_xor(sq, 32, 64);
            if (lane < 16) {
                unsafeAtomicAdd(&stats[col], s);
                unsafeAtomicAdd(&stats[256 + col], sq);
            }
        }
    }
    __syncthreads();
    constexpr int CPR = NOUT / 8;       // 16B chunks per row
    constexpr int TOT = 64 * CPR;
    #pragma unroll
    for (int i = 0; i < TOT / 256; ++i) {
        int idx = i * 256 + threadIdx.x;
        int row = idx / CPR;
        int ch = idx % CPR;
        if (row0 + row < M)
            *(bf16x8*)(C + (size_t)(row0 + row) * NOUT + ch * 8) =
                *(const bf16x8*)(lds + row * LROW + ch * 8);
    }
}

__global__ void k_bnfinal(const float* __restrict__ stats, const float* __restrict__ gamma,
                          const float* __restrict__ beta, float* __restrict__ scsh, int N) {
    int c = threadIdx.x;
    float invN = 1.0f / (float)N;
    float mean = stats[c] * invN;
    float var = stats[256 + c] * invN - mean * mean;
    var = fmaxf(var, 0.f);
    float inv = rsqrtf(var + BN_EPS);
    float sc = gamma[c] * inv;
    scsh[c] = sc;
    scsh[256 + c] = fmaf(-mean, sc, beta[c]);
}

extern "C" void kernel_launch(void* const* d_in, const int* in_sizes, int n_in,
                              void* d_out, int out_size, void* d_ws, size_t ws_size,
                              hipStream_t stream) {
    const float* nf    = (const float*)d_in[0];
    const int*   ei    = (const int*)d_in[1];
    const float* W1    = (const float*)d_in[2];
    const float* b1    = (const float*)d_in[3];
    const float* gamma = (const float*)d_in[4];
    const float* beta  = (const float*)d_in[5];
    const float* W2    = (const float*)d_in[6];
    const float* b2    = (const float*)d_in[7];
    float* out = (float*)d_out;

    const int N = in_sizes[0] / CIN;      // 50000
    const int E = in_sizes[1] / 2;        // 800000
    const int* src = ei;
    const int* dst = ei + E;

    char* ws = (char*)d_ws;
    auto align256 = [](size_t x) { return (x + 255) & ~(size_t)255; };
    size_t off = 0;
    int*   degi = (int*)(ws + off);      off += align256((size_t)N * 4);
    float* dinv = (float*)(ws + off);    off += align256((size_t)N * 4);
    int*   rowstart = (int*)(ws + off);  off += align256((size_t)(N + 1) * 4);
    int*   cursor = (int*)(ws + off);    off += align256((size_t)N * 4);
    int*   blocksum = (int*)(ws + off);  off += align256(256 * 4);
    float* stats = (float*)(ws + off);   off += align256(512 * 4);
    float* scsh = (float*)(ws + off);    off += align256(512 * 4);
    short* W1Th = (short*)(ws + off);    off += align256(32768 * 2);
    short* W1Tl = (short*)(ws + off);    off += align256(32768 * 2);
    short* W2Th = (short*)(ws + off);    off += align256(32768 * 2);
    short* W2Tl = (short*)(ws + off);    off += align256(32768 * 2);
    int*   csr_src = (int*)(ws + off);   off += align256((size_t)E * 4);
    float* csr_w = (float*)(ws + off);   off += align256((size_t)E * 4);
    short* nfb = (short*)(ws + off);     off += align256((size_t)N * CIN * 2);   // nf bf16
    short* agg1b = (short*)(ws + off);   off += align256((size_t)N * CIN * 2);   // S@x bf16
    short* x1b = (short*)(ws + off);     off += align256((size_t)N * CH * 2);    // layer1 bf16
    short* yb = (short*)(ws + off);      off += align256((size_t)N * COUT * 2);  // bnrelu(x1)@W2 bf16

    int nbN = (N + 255) / 256;
    int nbE = (E + 255) / 256;

    // degree + norm
    k_init<<<nbN, 256, 0, stream>>>(degi, stats, N);
    k_deg<<<nbE, 256, 0, stream>>>(dst, degi, E);
    k_dinv<<<nbN, 256, 0, stream>>>(degi, dinv, N);

    // CSR build
    k_scan1<<<nbN, 256, 0, stream>>>(degi, blocksum, N);
    k_scan2<<<1, 256, 0, stream>>>(blocksum, nbN, rowstart, N, E);
    k_scan3<<<nbN, 256, 0, stream>>>(degi, blocksum, rowstart, cursor, N);
    k_fill<<<nbE, 256, 0, stream>>>(src, dst, dinv, cursor, csr_src, csr_w, E);

    // weight transpose + split; node features -> bf16
    k_wprep<<<256, 256, 0, stream>>>(W1, W2, W1Th, W1Tl, W2Th, W2Tl);
    k_tobf<<<(N * 32 + 255) / 256, 256, 0, stream>>>((const float4*)nf, (short4*)nfb, N * 32);

    // layer 1 aggregation (gather, bf16 in/out)
    k_gather<0><<<(N * 32 + 255) / 256, 256, 0, stream>>>(
        nfb, rowstart, csr_src, csr_w, dinv, nullptr, nullptr, agg1b, N);

    // x1 = agg1 @ W1 + b1, fused BN stats
    k_gemm<CIN, CH, true, true, false><<<(N + 63) / 64, 256, 0, stream>>>(
        agg1b, W1Th, W1Tl, b1, nullptr, x1b, stats, N);

    // BN scale/shift
    k_bnfinal<<<1, 256, 0, stream>>>(stats, gamma, beta, scsh, N);

    // y = relu(bn(x1)) @ W2  (BN+ReLU fused into A-load; bias deferred to gather)
    k_gemm<CH, COUT, false, false, true><<<(N + 63) / 64, 256, 0, stream>>>(
        x1b, W2Th, W2Tl, nullptr, scsh, yb, nullptr, N);

    // out = S @ y + b2
    k_gather<1><<<(N * 32 + 255) / 256, 256, 0, stream>>>(
        yb, rowstart, csr_src, csr_w, dinv, (const float4*)b2, (float4*)out, nullptr, N);
}

// Round 6
// 319.521 us; speedup vs baseline: 9.5903x; 1.0616x over previous
//
#include <hip/hip_runtime.h>

#define CIN 128
#define CH 256
#define COUT 128
#define BN_EPS 1e-5f

typedef __attribute__((ext_vector_type(8))) short bf16x8;
typedef __attribute__((ext_vector_type(4))) float f32x4;

// float -> bf16 (round-to-nearest-even), raw short
__device__ __forceinline__ short f2bf(float x) {
    unsigned u = __float_as_uint(x);
    unsigned r = (u + 0x7fffu + ((u >> 16) & 1u)) >> 16;
    return (short)r;
}
__device__ __forceinline__ float bf2f(short h) {
    return __uint_as_float(((unsigned)(unsigned short)h) << 16);
}

__global__ void k_deg(const int* __restrict__ dst, int* __restrict__ degi, int E) {
    int e = blockIdx.x * 256 + threadIdx.x;
    if (e < E) atomicAdd(&degi[dst[e]], 1);
}

// block sums of degi + fused dinv = rsqrt(deg+1)
__global__ void k_scan1(const int* __restrict__ degi, float* __restrict__ dinv,
                        int* __restrict__ blocksum, int N) {
    __shared__ int s[256];
    int i = blockIdx.x * 256 + threadIdx.x;
    int v = (i < N) ? degi[i] : 0;
    if (i < N) dinv[i] = rsqrtf((float)(v + 1));
    s[threadIdx.x] = v;
    __syncthreads();
    for (int st = 128; st > 0; st >>= 1) {
        if (threadIdx.x < st) s[threadIdx.x] += s[threadIdx.x + st];
        __syncthreads();
    }
    if (threadIdx.x == 0) blocksum[blockIdx.x] = s[0];
}

__global__ void k_scan2(int* __restrict__ blocksum, int nb,
                        int* __restrict__ rowstart, int N, int E) {
    __shared__ int s[256];
    int v = (threadIdx.x < nb) ? blocksum[threadIdx.x] : 0;
    s[threadIdx.x] = v;
    __syncthreads();
    for (int st = 1; st < 256; st <<= 1) {
        int t = (threadIdx.x >= st) ? s[threadIdx.x - st] : 0;
        __syncthreads();
        s[threadIdx.x] += t;
        __syncthreads();
    }
    if (threadIdx.x < nb) blocksum[threadIdx.x] = s[threadIdx.x] - v;
    if (threadIdx.x == 0) rowstart[N] = E;
}

__global__ void k_scan3(const int* __restrict__ degi, const int* __restrict__ blockoff,
                        int* __restrict__ rowstart, int* __restrict__ cursor, int N) {
    __shared__ int s[256];
    int i = blockIdx.x * 256 + threadIdx.x;
    int v = (i < N) ? degi[i] : 0;
    s[threadIdx.x] = v;
    __syncthreads();
    for (int st = 1; st < 256; st <<= 1) {
        int t = (threadIdx.x >= st) ? s[threadIdx.x - st] : 0;
        __syncthreads();
        s[threadIdx.x] += t;
        __syncthreads();
    }
    if (i < N) {
        int ex = s[threadIdx.x] - v + blockoff[blockIdx.x];
        rowstart[i] = ex;
        cursor[i] = ex;
    }
}

// place each edge into its dst bucket as one packed 8B record (src, weight)
__global__ void k_fill(const int* __restrict__ src, const int* __restrict__ dst,
                       const float* __restrict__ dinv, int* __restrict__ cursor,
                       int2* __restrict__ csr, int E) {
    int e = blockIdx.x * 256 + threadIdx.x;
    if (e >= E) return;
    int s = src[e];
    int d = dst[e];
    int pos = atomicAdd(&cursor[d], 1);
    int2 rec;
    rec.x = s;
    rec.y = __float_as_int(dinv[s] * dinv[d]);
    csr[pos] = rec;
}

// fused: transpose+split W1,W2 and cast node features to bf16
__global__ void k_prep(const float* __restrict__ W1, const float* __restrict__ W2,
                       short* __restrict__ W1Th, short* __restrict__ W1Tl,
                       short* __restrict__ W2Th, short* __restrict__ W2Tl,
                       const float4* __restrict__ nf, short4* __restrict__ nfb, int n4) {
    int t = blockIdx.x * 256 + threadIdx.x;
    if (t < 32768) {                 // W1 [128][256] -> W1T [256][128]
        int n = t >> 7, k = t & 127;
        float v = W1[k * 256 + n];
        short h = f2bf(v);
        W1Th[t] = h;
        W1Tl[t] = f2bf(v - bf2f(h));
    } else if (t < 65536) {          // W2 [256][128] -> W2T [128][256]
        int u = t - 32768;
        int n = u >> 8, k = u & 255;
        float v = W2[k * 128 + n];
        short h = f2bf(v);
        W2Th[u] = h;
        W2Tl[u] = f2bf(v - bf2f(h));
    } else {
        int u = t - 65536;
        if (u < n4) {
            float4 v = nf[u];
            short4 s;
            s.x = f2bf(v.x); s.y = f2bf(v.y); s.z = f2bf(v.z); s.w = f2bf(v.w);
            nfb[u] = s;
        }
    }
}

// gather over CSR, bf16 input rows [N,128], fp32 accumulate.
// 16 lanes per row, 8 channels (16B) per lane, 4-edge unroll.
// MODE 0: write bf16 row; MODE 1: write fp32 + bias (final output)
template <int MODE>
__global__ __launch_bounds__(256) void k_gather(const short* __restrict__ xb,
                                                const int* __restrict__ rowstart,
                                                const int2* __restrict__ csr,
                                                const float* __restrict__ dinv,
                                                const float* __restrict__ bias,
                                                float* __restrict__ out,
                                                short* __restrict__ ob, int N) {
    int t = blockIdx.x * 256 + threadIdx.x;
    int r = t >> 4;
    int c = t & 15;              // channels c*8 .. c*8+7
    if (r >= N) return;
    float di = dinv[r];
    float w0 = di * di;
    bf16x8 sv = *(const bf16x8*)(xb + (size_t)r * 128 + c * 8);
    float acc[8];
    #pragma unroll
    for (int j = 0; j < 8; ++j) acc[j] = bf2f(sv[j]) * w0;
    int e0 = rowstart[r], e1 = rowstart[r + 1];
    int e = e0;
    for (; e + 3 < e1; e += 4) {
        int2 c0 = csr[e], c1 = csr[e + 1], c2 = csr[e + 2], c3 = csr[e + 3];
        bf16x8 x0 = *(const bf16x8*)(xb + (size_t)c0.x * 128 + c * 8);
        bf16x8 x1 = *(const bf16x8*)(xb + (size_t)c1.x * 128 + c * 8);
        bf16x8 x2 = *(const bf16x8*)(xb + (size_t)c2.x * 128 + c * 8);
        bf16x8 x3 = *(const bf16x8*)(xb + (size_t)c3.x * 128 + c * 8);
        float w0_ = __int_as_float(c0.y);
        float w1_ = __int_as_float(c1.y);
        float w2_ = __int_as_float(c2.y);
        float w3_ = __int_as_float(c3.y);
        #pragma unroll
        for (int j = 0; j < 8; ++j) {
            acc[j] = fmaf(w0_, bf2f(x0[j]), acc[j]);
            acc[j] = fmaf(w1_, bf2f(x1[j]), acc[j]);
            acc[j] = fmaf(w2_, bf2f(x2[j]), acc[j]);
            acc[j] = fmaf(w3_, bf2f(x3[j]), acc[j]);
        }
    }
    for (; e < e1; ++e) {
        int2 ce = csr[e];
        bf16x8 x0 = *(const bf16x8*)(xb + (size_t)ce.x * 128 + c * 8);
        float ww = __int_as_float(ce.y);
        #pragma unroll
        for (int j = 0; j < 8; ++j) acc[j] = fmaf(ww, bf2f(x0[j]), acc[j]);
    }
    if (MODE == 0) {
        bf16x8 h;
        #pragma unroll
        for (int j = 0; j < 8; ++j) h[j] = f2bf(acc[j]);
        *(bf16x8*)(ob + (size_t)r * 128 + c * 8) = h;
    } else {
        float4 b0 = *(const float4*)(bias + c * 8);
        float4 b1 = *(const float4*)(bias + c * 8 + 4);
        float4 o0 = make_float4(acc[0] + b0.x, acc[1] + b0.y, acc[2] + b0.z, acc[3] + b0.w);
        float4 o1 = make_float4(acc[4] + b1.x, acc[5] + b1.y, acc[6] + b1.z, acc[7] + b1.w);
        *(float4*)(out + (size_t)r * 128 + c * 8) = o0;
        *(float4*)(out + (size_t)r * 128 + c * 8 + 4) = o1;
    }
}

__device__ __forceinline__ bf16x8 bnrelu8(bf16x8 raw, const float* __restrict__ scsh, int c) {
    float4 sc0 = *(const float4*)(scsh + c);
    float4 sc1 = *(const float4*)(scsh + c + 4);
    float4 sh0 = *(const float4*)(scsh + 256 + c);
    float4 sh1 = *(const float4*)(scsh + 256 + c + 4);
    bf16x8 o;
    o[0] = f2bf(fmaxf(fmaf(bf2f(raw[0]), sc0.x, sh0.x), 0.f));
    o[1] = f2bf(fmaxf(fmaf(bf2f(raw[1]), sc0.y, sh0.y), 0.f));
    o[2] = f2bf(fmaxf(fmaf(bf2f(raw[2]), sc0.z, sh0.z), 0.f));
    o[3] = f2bf(fmaxf(fmaf(bf2f(raw[3]), sc0.w, sh0.w), 0.f));
    o[4] = f2bf(fmaxf(fmaf(bf2f(raw[4]), sc1.x, sh1.x), 0.f));
    o[5] = f2bf(fmaxf(fmaf(bf2f(raw[5]), sc1.y, sh1.y), 0.f));
    o[6] = f2bf(fmaxf(fmaf(bf2f(raw[6]), sc1.z, sh1.z), 0.f));
    o[7] = f2bf(fmaxf(fmaf(bf2f(raw[7]), sc1.w, sh1.w), 0.f));
    return o;
}

// C[M,NOUT](bf16) = f(A)[M,K](bf16) @ (Bh+Bl)^T[NOUT,K] + bias
// f = identity or BN+ReLU (scsh). Optional fused BN stats on output.
// Block: 256 thr = 4 waves, 64 rows x full NOUT. Wave: 64 rows x NOUT/4 cols.
// B-fragments preloaded to registers; epilogue staged via LDS for coalesced
// 16B row writes (avoids partial-sector write amplification).
template <int K, int NOUT, bool STATS, bool BIAS, bool BNRELU>
__global__ __launch_bounds__(256, 2) void k_gemm(const short* __restrict__ A,
                                                 const short* __restrict__ Bh,
                                                 const short* __restrict__ Bl,
                                                 const float* __restrict__ bias,
                                                 const float* __restrict__ scsh,
                                                 short* __restrict__ C,
                                                 float* __restrict__ stats, int M) {
    constexpr int CT = NOUT / 64;   // col-tiles per wave
    constexpr int KS = K / 32;      // k-steps
    constexpr int LROW = NOUT + 8;  // padded LDS row (shorts)
    __shared__ short lds[64 * LROW];
    int wave = threadIdx.x >> 6;
    int lane = threadIdx.x & 63;
    int m = lane & 15;
    int q = lane >> 4;
    int row0 = blockIdx.x * 64;
    int colw = wave * (NOUT / 4);

    // preload all B fragments for this wave into registers
    bf16x8 bhf[CT][KS], blf[CT][KS];
    #pragma unroll
    for (int ct = 0; ct < CT; ++ct) {
        #pragma unroll
        for (int ks = 0; ks < KS; ++ks) {
            size_t bo = (size_t)(colw + ct * 16 + m) * K + ks * 32 + q * 8;
            bhf[ct][ks] = *(const bf16x8*)(Bh + bo);
            blf[ct][ks] = *(const bf16x8*)(Bl + bo);
        }
    }

    const short* pa[4];
    #pragma unroll
    for (int rt = 0; rt < 4; ++rt) {
        int ar = row0 + rt * 16 + m;
        if (ar >= M) ar = M - 1;
        pa[rt] = A + (size_t)ar * K + q * 8;
    }

    f32x4 acc[4][CT];
    #pragma unroll
    for (int rt = 0; rt < 4; ++rt)
        #pragma unroll
        for (int ct = 0; ct < CT; ++ct)
            acc[rt][ct] = (f32x4){0.f, 0.f, 0.f, 0.f};

    #pragma unroll
    for (int ks = 0; ks < KS; ++ks) {
        bf16x8 af[4];
        #pragma unroll
        for (int rt = 0; rt < 4; ++rt) {
            bf16x8 raw = *(const bf16x8*)(pa[rt] + ks * 32);
            af[rt] = BNRELU ? bnrelu8(raw, scsh, ks * 32 + q * 8) : raw;
        }
        #pragma unroll
        for (int ct = 0; ct < CT; ++ct) {
            #pragma unroll
            for (int rt = 0; rt < 4; ++rt) {
                acc[rt][ct] = __builtin_amdgcn_mfma_f32_16x16x32_bf16(af[rt], bhf[ct][ks], acc[rt][ct], 0, 0, 0);
                acc[rt][ct] = __builtin_amdgcn_mfma_f32_16x16x32_bf16(af[rt], blf[ct][ks], acc[rt][ct], 0, 0, 0);
            }
        }
    }

    // epilogue: bias (+stats), bf16 -> LDS, then coalesced global writes
    #pragma unroll
    for (int ct = 0; ct < CT; ++ct) {
        int col = colw + ct * 16 + m;
        float bv = BIAS ? bias[col] : 0.f;
        float s = 0.f, sq = 0.f;
        #pragma unroll
        for (int rt = 0; rt < 4; ++rt) {
            #pragma unroll
            for (int r = 0; r < 4; ++r) {
                int lrow = rt * 16 + q * 4 + r;
                float v = acc[rt][ct][r] + bv;
                if (STATS && row0 + lrow < M) { s += v; sq = fmaf(v, v, sq); }
                lds[lrow * LROW + col] = f2bf(v);
            }
        }
        if (STATS) {
            s += __shfl_xor(s, 16, 64);
            s += __shfl_xor(s, 32, 64);
            sq += __shfl_xor(sq, 16, 64);
            sq += __shfl_xor(sq, 32, 64);
            if (lane < 16) {
                unsafeAtomicAdd(&stats[col], s);
                unsafeAtomicAdd(&stats[256 + col], sq);
            }
        }
    }
    __syncthreads();
    constexpr int CPR = NOUT / 8;       // 16B chunks per row
    constexpr int TOT = 64 * CPR;
    #pragma unroll
    for (int i = 0; i < TOT / 256; ++i) {
        int idx = i * 256 + threadIdx.x;
        int row = idx / CPR;
        int ch = idx % CPR;
        if (row0 + row < M)
            *(bf16x8*)(C + (size_t)(row0 + row) * NOUT + ch * 8) =
                *(const bf16x8*)(lds + row * LROW + ch * 8);
    }
}

__global__ void k_bnfinal(const float* __restrict__ stats, const float* __restrict__ gamma,
                          const float* __restrict__ beta, float* __restrict__ scsh, int N) {
    int c = threadIdx.x;
    float invN = 1.0f / (float)N;
    float mean = stats[c] * invN;
    float var = stats[256 + c] * invN - mean * mean;
    var = fmaxf(var, 0.f);
    float inv = rsqrtf(var + BN_EPS);
    float sc = gamma[c] * inv;
    scsh[c] = sc;
    scsh[256 + c] = fmaf(-mean, sc, beta[c]);
}

extern "C" void kernel_launch(void* const* d_in, const int* in_sizes, int n_in,
                              void* d_out, int out_size, void* d_ws, size_t ws_size,
                              hipStream_t stream) {
    const float* nf    = (const float*)d_in[0];
    const int*   ei    = (const int*)d_in[1];
    const float* W1    = (const float*)d_in[2];
    const float* b1    = (const float*)d_in[3];
    const float* gamma = (const float*)d_in[4];
    const float* beta  = (const float*)d_in[5];
    const float* W2    = (const float*)d_in[6];
    const float* b2    = (const float*)d_in[7];
    float* out = (float*)d_out;

    const int N = in_sizes[0] / CIN;      // 50000
    const int E = in_sizes[1] / 2;        // 800000
    const int* src = ei;
    const int* dst = ei + E;

    char* ws = (char*)d_ws;
    auto align256 = [](size_t x) { return (x + 255) & ~(size_t)255; };
    size_t off = 0;
    int*   degi = (int*)(ws + off);      off += align256((size_t)N * 4);
    float* stats = (float*)(ws + off);   off += align256(512 * 4);
    size_t zspan = off;                  // memset degi+stats in one shot
    float* dinv = (float*)(ws + off);    off += align256((size_t)N * 4);
    int*   rowstart = (int*)(ws + off);  off += align256((size_t)(N + 1) * 4);
    int*   cursor = (int*)(ws + off);    off += align256((size_t)N * 4);
    int*   blocksum = (int*)(ws + off);  off += align256(256 * 4);
    float* scsh = (float*)(ws + off);    off += align256(512 * 4);
    short* W1Th = (short*)(ws + off);    off += align256(32768 * 2);
    short* W1Tl = (short*)(ws + off);    off += align256(32768 * 2);
    short* W2Th = (short*)(ws + off);    off += align256(32768 * 2);
    short* W2Tl = (short*)(ws + off);    off += align256(32768 * 2);
    int2*  csr = (int2*)(ws + off);      off += align256((size_t)E * 8);
    short* nfb = (short*)(ws + off);     off += align256((size_t)N * CIN * 2);   // nf bf16
    short* agg1b = (short*)(ws + off);   off += align256((size_t)N * CIN * 2);   // S@x bf16
    short* x1b = (short*)(ws + off);     off += align256((size_t)N * CH * 2);    // layer1 bf16
    short* yb = (short*)(ws + off);      off += align256((size_t)N * COUT * 2);  // bnrelu(x1)@W2 bf16

    int nbN = (N + 255) / 256;
    int nbE = (E + 255) / 256;
    int n4 = N * 32;

    // zero degi + stats in one memset
    hipMemsetAsync(ws, 0, zspan, stream);

    // weight prep + feature cast (independent of graph build)
    k_prep<<<(65536 + n4 + 255) / 256, 256, 0, stream>>>(
        W1, W2, W1Th, W1Tl, W2Th, W2Tl, (const float4*)nf, (short4*)nfb, n4);

    // degree + norm + CSR build
    k_deg<<<nbE, 256, 0, stream>>>(dst, degi, E);
    k_scan1<<<nbN, 256, 0, stream>>>(degi, dinv, blocksum, N);
    k_scan2<<<1, 256, 0, stream>>>(blocksum, nbN, rowstart, N, E);
    k_scan3<<<nbN, 256, 0, stream>>>(degi, blocksum, rowstart, cursor, N);
    k_fill<<<nbE, 256, 0, stream>>>(src, dst, dinv, cursor, csr, E);

    // layer 1 aggregation (gather, bf16 in/out)
    k_gather<0><<<(N * 16 + 255) / 256, 256, 0, stream>>>(
        nfb, rowstart, csr, dinv, nullptr, nullptr, agg1b, N);

    // x1 = agg1 @ W1 + b1, fused BN stats
    k_gemm<CIN, CH, true, true, false><<<(N + 63) / 64, 256, 0, stream>>>(
        agg1b, W1Th, W1Tl, b1, nullptr, x1b, stats, N);

    // BN scale/shift
    k_bnfinal<<<1, 256, 0, stream>>>(stats, gamma, beta, scsh, N);

    // y = relu(bn(x1)) @ W2  (BN+ReLU fused into A-load; bias deferred to gather)
    k_gemm<CH, COUT, false, false, true><<<(N + 63) / 64, 256, 0, stream>>>(
        x1b, W2Th, W2Tl, nullptr, scsh, yb, nullptr, N);

    // out = S @ y + b2
    k_gather<1><<<(N * 16 + 255) / 256, 256, 0, stream>>>(
        yb, rowstart, csr, dinv, b2, out, nullptr, N);
}

// Round 7
// 319.081 us; speedup vs baseline: 9.6035x; 1.0014x over previous
//
#include <hip/hip_runtime.h>
#include <hip/hip_fp16.h>

#define CIN 128
#define CH 256
#define COUT 128
#define BN_EPS 1e-5f

typedef __attribute__((ext_vector_type(8))) short bf16x8;
typedef __attribute__((ext_vector_type(4))) float f32x4;

// float -> bf16 (round-to-nearest-even), raw short
__device__ __forceinline__ short f2bf(float x) {
    unsigned u = __float_as_uint(x);
    unsigned r = (u + 0x7fffu + ((u >> 16) & 1u)) >> 16;
    return (short)r;
}
__device__ __forceinline__ float bf2f(short h) {
    return __uint_as_float(((unsigned)(unsigned short)h) << 16);
}

__global__ void k_deg(const int* __restrict__ dst, int* __restrict__ degi, int E) {
    int e = blockIdx.x * 256 + threadIdx.x;
    if (e < E) atomicAdd(&degi[dst[e]], 1);
}

// block sums of degi + fused dinv = rsqrt(deg+1)
__global__ void k_scan1(const int* __restrict__ degi, float* __restrict__ dinv,
                        int* __restrict__ blocksum, int N) {
    __shared__ int s[256];
    int i = blockIdx.x * 256 + threadIdx.x;
    int v = (i < N) ? degi[i] : 0;
    if (i < N) dinv[i] = rsqrtf((float)(v + 1));
    s[threadIdx.x] = v;
    __syncthreads();
    for (int st = 128; st > 0; st >>= 1) {
        if (threadIdx.x < st) s[threadIdx.x] += s[threadIdx.x + st];
        __syncthreads();
    }
    if (threadIdx.x == 0) blocksum[blockIdx.x] = s[0];
}

// per-element exclusive scan; every block redundantly scans blocksum in LDS
// (folds the old k_scan2). nb <= 256.
__global__ void k_scan3(const int* __restrict__ degi, const int* __restrict__ blocksum,
                        int nb, int* __restrict__ rowstart, int* __restrict__ cursor,
                        int N, int E) {
    __shared__ int sb[256];
    __shared__ int s[256];
    int bv = (threadIdx.x < nb) ? blocksum[threadIdx.x] : 0;
    sb[threadIdx.x] = bv;
    __syncthreads();
    for (int st = 1; st < 256; st <<= 1) {
        int t = (threadIdx.x >= st) ? sb[threadIdx.x - st] : 0;
        __syncthreads();
        sb[threadIdx.x] += t;
        __syncthreads();
    }
    int boff = (blockIdx.x == 0) ? 0 : sb[blockIdx.x - 1];

    int i = blockIdx.x * 256 + threadIdx.x;
    int v = (i < N) ? degi[i] : 0;
    s[threadIdx.x] = v;
    __syncthreads();
    for (int st = 1; st < 256; st <<= 1) {
        int t = (threadIdx.x >= st) ? s[threadIdx.x - st] : 0;
        __syncthreads();
        s[threadIdx.x] += t;
        __syncthreads();
    }
    if (i < N) {
        int ex = s[threadIdx.x] - v + boff;
        rowstart[i] = ex;
        cursor[i] = ex;
    }
    if (blockIdx.x == 0 && threadIdx.x == 0) rowstart[N] = E;
}

// place each edge into its dst bucket as one packed 4B record (src16 | fp16 w)
__global__ void k_fill(const int* __restrict__ src, const int* __restrict__ dst,
                       const float* __restrict__ dinv, int* __restrict__ cursor,
                       unsigned* __restrict__ csr, int E) {
    int e = blockIdx.x * 256 + threadIdx.x;
    if (e >= E) return;
    int s = src[e];
    int d = dst[e];
    int pos = atomicAdd(&cursor[d], 1);
    float w = dinv[s] * dinv[d];
    unsigned h = (unsigned)__half_as_ushort(__float2half(w));
    csr[pos] = ((unsigned)s << 16) | h;
}

// fused: transpose+split W1,W2 and cast node features to bf16
__global__ void k_prep(const float* __restrict__ W1, const float* __restrict__ W2,
                       short* __restrict__ W1Th, short* __restrict__ W1Tl,
                       short* __restrict__ W2Th, short* __restrict__ W2Tl,
                       const float4* __restrict__ nf, short4* __restrict__ nfb, int n4) {
    int t = blockIdx.x * 256 + threadIdx.x;
    if (t < 32768) {                 // W1 [128][256] -> W1T [256][128]
        int n = t >> 7, k = t & 127;
        float v = W1[k * 256 + n];
        short h = f2bf(v);
        W1Th[t] = h;
        W1Tl[t] = f2bf(v - bf2f(h));
    } else if (t < 65536) {          // W2 [256][128] -> W2T [128][256]
        int u = t - 32768;
        int n = u >> 8, k = u & 255;
        float v = W2[k * 128 + n];
        short h = f2bf(v);
        W2Th[u] = h;
        W2Tl[u] = f2bf(v - bf2f(h));
    } else {
        int u = t - 65536;
        if (u < n4) {
            float4 v = nf[u];
            short4 s;
            s.x = f2bf(v.x); s.y = f2bf(v.y); s.z = f2bf(v.z); s.w = f2bf(v.w);
            nfb[u] = s;
        }
    }
}

__device__ __forceinline__ void unpack(unsigned rec, int& s, float& w) {
    s = rec >> 16;
    w = __half2float(__ushort_as_half((unsigned short)(rec & 0xffffu)));
}

// gather over CSR, bf16 input rows [N,128], fp32 accumulate.
// 16 lanes per row, 8 channels (16B) per lane; 8/4/1 edge unroll for MLP.
// MODE 0: write bf16 row; MODE 1: write fp32 + bias (final output)
template <int MODE>
__global__ __launch_bounds__(256) void k_gather(const short* __restrict__ xb,
                                                const int* __restrict__ rowstart,
                                                const unsigned* __restrict__ csr,
                                                const float* __restrict__ dinv,
                                                const float* __restrict__ bias,
                                                float* __restrict__ out,
                                                short* __restrict__ ob, int N) {
    int t = blockIdx.x * 256 + threadIdx.x;
    int r = t >> 4;
    int c = t & 15;              // channels c*8 .. c*8+7
    if (r >= N) return;
    float di = dinv[r];
    float w0 = di * di;
    bf16x8 sv = *(const bf16x8*)(xb + (size_t)r * 128 + c * 8);
    float acc[8];
    #pragma unroll
    for (int j = 0; j < 8; ++j) acc[j] = bf2f(sv[j]) * w0;
    int e0 = rowstart[r], e1 = rowstart[r + 1];
    int e = e0;
    for (; e + 7 < e1; e += 8) {
        int s[8]; float w[8];
        #pragma unroll
        for (int i = 0; i < 8; ++i) unpack(csr[e + i], s[i], w[i]);
        bf16x8 x[8];
        #pragma unroll
        for (int i = 0; i < 8; ++i) x[i] = *(const bf16x8*)(xb + (size_t)s[i] * 128 + c * 8);
        #pragma unroll
        for (int i = 0; i < 8; ++i)
            #pragma unroll
            for (int j = 0; j < 8; ++j) acc[j] = fmaf(w[i], bf2f(x[i][j]), acc[j]);
    }
    for (; e + 3 < e1; e += 4) {
        int s[4]; float w[4];
        #pragma unroll
        for (int i = 0; i < 4; ++i) unpack(csr[e + i], s[i], w[i]);
        bf16x8 x[4];
        #pragma unroll
        for (int i = 0; i < 4; ++i) x[i] = *(const bf16x8*)(xb + (size_t)s[i] * 128 + c * 8);
        #pragma unroll
        for (int i = 0; i < 4; ++i)
            #pragma unroll
            for (int j = 0; j < 8; ++j) acc[j] = fmaf(w[i], bf2f(x[i][j]), acc[j]);
    }
    for (; e < e1; ++e) {
        int s0; float ww;
        unpack(csr[e], s0, ww);
        bf16x8 x0 = *(const bf16x8*)(xb + (size_t)s0 * 128 + c * 8);
        #pragma unroll
        for (int j = 0; j < 8; ++j) acc[j] = fmaf(ww, bf2f(x0[j]), acc[j]);
    }
    if (MODE == 0) {
        bf16x8 h;
        #pragma unroll
        for (int j = 0; j < 8; ++j) h[j] = f2bf(acc[j]);
        *(bf16x8*)(ob + (size_t)r * 128 + c * 8) = h;
    } else {
        float4 b0 = *(const float4*)(bias + c * 8);
        float4 b1 = *(const float4*)(bias + c * 8 + 4);
        float4 o0 = make_float4(acc[0] + b0.x, acc[1] + b0.y, acc[2] + b0.z, acc[3] + b0.w);
        float4 o1 = make_float4(acc[4] + b1.x, acc[5] + b1.y, acc[6] + b1.z, acc[7] + b1.w);
        *(float4*)(out + (size_t)r * 128 + c * 8) = o0;
        *(float4*)(out + (size_t)r * 128 + c * 8 + 4) = o1;
    }
}

__device__ __forceinline__ bf16x8 bnrelu8(bf16x8 raw, const float* __restrict__ scsh, int c) {
    float4 sc0 = *(const float4*)(scsh + c);
    float4 sc1 = *(const float4*)(scsh + c + 4);
    float4 sh0 = *(const float4*)(scsh + 256 + c);
    float4 sh1 = *(const float4*)(scsh + 256 + c + 4);
    bf16x8 o;
    o[0] = f2bf(fmaxf(fmaf(bf2f(raw[0]), sc0.x, sh0.x), 0.f));
    o[1] = f2bf(fmaxf(fmaf(bf2f(raw[1]), sc0.y, sh0.y), 0.f));
    o[2] = f2bf(fmaxf(fmaf(bf2f(raw[2]), sc0.z, sh0.z), 0.f));
    o[3] = f2bf(fmaxf(fmaf(bf2f(raw[3]), sc0.w, sh0.w), 0.f));
    o[4] = f2bf(fmaxf(fmaf(bf2f(raw[4]), sc1.x, sh1.x), 0.f));
    o[5] = f2bf(fmaxf(fmaf(bf2f(raw[5]), sc1.y, sh1.y), 0.f));
    o[6] = f2bf(fmaxf(fmaf(bf2f(raw[6]), sc1.z, sh1.z), 0.f));
    o[7] = f2bf(fmaxf(fmaf(bf2f(raw[7]), sc1.w, sh1.w), 0.f));
    return o;
}

// C[M,NOUT](bf16) = f(A)[M,K](bf16) @ (Bh+Bl)^T[NOUT,K] + bias
// f = identity or BN+ReLU (scsh). Optional fused BN stats on output.
// Block: 256 thr = 4 waves, 64 rows x full NOUT. Wave: 64 rows x NOUT/4 cols.
// B-fragments preloaded to registers; epilogue staged via LDS for coalesced
// 16B row writes (avoids partial-sector write amplification).
template <int K, int NOUT, bool STATS, bool BIAS, bool BNRELU>
__global__ __launch_bounds__(256, 2) void k_gemm(const short* __restrict__ A,
                                                 const short* __restrict__ Bh,
                                                 const short* __restrict__ Bl,
                                                 const float* __restrict__ bias,
                                                 const float* __restrict__ scsh,
                                                 short* __restrict__ C,
                                                 float* __restrict__ stats, int M) {
    constexpr int CT = NOUT / 64;   // col-tiles per wave
    constexpr int KS = K / 32;      // k-steps
    constexpr int LROW = NOUT + 8;  // padded LDS row (shorts)
    __shared__ short lds[64 * LROW];
    int wave = threadIdx.x >> 6;
    int lane = threadIdx.x & 63;
    int m = lane & 15;
    int q = lane >> 4;
    int row0 = blockIdx.x * 64;
    int colw = wave * (NOUT / 4);

    // preload all B fragments for this wave into registers
    bf16x8 bhf[CT][KS], blf[CT][KS];
    #pragma unroll
    for (int ct = 0; ct < CT; ++ct) {
        #pragma unroll
        for (int ks = 0; ks < KS; ++ks) {
            size_t bo = (size_t)(colw + ct * 16 + m) * K + ks * 32 + q * 8;
            bhf[ct][ks] = *(const bf16x8*)(Bh + bo);
            blf[ct][ks] = *(const bf16x8*)(Bl + bo);
        }
    }

    const short* pa[4];
    #pragma unroll
    for (int rt = 0; rt < 4; ++rt) {
        int ar = row0 + rt * 16 + m;
        if (ar >= M) ar = M - 1;
        pa[rt] = A + (size_t)ar * K + q * 8;
    }

    f32x4 acc[4][CT];
    #pragma unroll
    for (int rt = 0; rt < 4; ++rt)
        #pragma unroll
        for (int ct = 0; ct < CT; ++ct)
            acc[rt][ct] = (f32x4){0.f, 0.f, 0.f, 0.f};

    #pragma unroll
    for (int ks = 0; ks < KS; ++ks) {
        bf16x8 af[4];
        #pragma unroll
        for (int rt = 0; rt < 4; ++rt) {
            bf16x8 raw = *(const bf16x8*)(pa[rt] + ks * 32);
            af[rt] = BNRELU ? bnrelu8(raw, scsh, ks * 32 + q * 8) : raw;
        }
        #pragma unroll
        for (int ct = 0; ct < CT; ++ct) {
            #pragma unroll
            for (int rt = 0; rt < 4; ++rt) {
                acc[rt][ct] = __builtin_amdgcn_mfma_f32_16x16x32_bf16(af[rt], bhf[ct][ks], acc[rt][ct], 0, 0, 0);
                acc[rt][ct] = __builtin_amdgcn_mfma_f32_16x16x32_bf16(af[rt], blf[ct][ks], acc[rt][ct], 0, 0, 0);
            }
        }
    }

    // epilogue: bias (+stats), bf16 -> LDS, then coalesced global writes
    #pragma unroll
    for (int ct = 0; ct < CT; ++ct) {
        int col = colw + ct * 16 + m;
        float bv = BIAS ? bias[col] : 0.f;
        float s = 0.f, sq = 0.f;
        #pragma unroll
        for (int rt = 0; rt < 4; ++rt) {
            #pragma unroll
            for (int r = 0; r < 4; ++r) {
                int lrow = rt * 16 + q * 4 + r;
                float v = acc[rt][ct][r] + bv;
                if (STATS && row0 + lrow < M) { s += v; sq = fmaf(v, v, sq); }
                lds[lrow * LROW + col] = f2bf(v);
            }
        }
        if (STATS) {
            s += __shfl_xor(s, 16, 64);
            s += __shfl_xor(s, 32, 64);
            sq += __shfl_xor(sq, 16, 64);
            sq += __shfl_xor(sq, 32, 64);
            if (lane < 16) {
                unsafeAtomicAdd(&stats[col], s);
                unsafeAtomicAdd(&stats[256 + col], sq);
            }
        }
    }
    __syncthreads();
    constexpr int CPR = NOUT / 8;       // 16B chunks per row
    constexpr int TOT = 64 * CPR;
    #pragma unroll
    for (int i = 0; i < TOT / 256; ++i) {
        int idx = i * 256 + threadIdx.x;
        int row = idx / CPR;
        int ch = idx % CPR;
        if (row0 + row < M)
            *(bf16x8*)(C + (size_t)(row0 + row) * NOUT + ch * 8) =
                *(const bf16x8*)(lds + row * LROW + ch * 8);
    }
}

__global__ void k_bnfinal(const float* __restrict__ stats, const float* __restrict__ gamma,
                          const float* __restrict__ beta, float* __restrict__ scsh, int N) {
    int c = threadIdx.x;
    float invN = 1.0f / (float)N;
    float mean = stats[c] * invN;
    float var = stats[256 + c] * invN - mean * mean;
    var = fmaxf(var, 0.f);
    float inv = rsqrtf(var + BN_EPS);
    float sc = gamma[c] * inv;
    scsh[c] = sc;
    scsh[256 + c] = fmaf(-mean, sc, beta[c]);
}

extern "C" void kernel_launch(void* const* d_in, const int* in_sizes, int n_in,
                              void* d_out, int out_size, void* d_ws, size_t ws_size,
                              hipStream_t stream) {
    const float* nf    = (const float*)d_in[0];
    const int*   ei    = (const int*)d_in[1];
    const float* W1    = (const float*)d_in[2];
    const float* b1    = (const float*)d_in[3];
    const float* gamma = (const float*)d_in[4];
    const float* beta  = (const float*)d_in[5];
    const float* W2    = (const float*)d_in[6];
    const float* b2    = (const float*)d_in[7];
    float* out = (float*)d_out;

    const int N = in_sizes[0] / CIN;      // 50000
    const int E = in_sizes[1] / 2;        // 800000
    const int* src = ei;
    const int* dst = ei + E;

    char* ws = (char*)d_ws;
    auto align256 = [](size_t x) { return (x + 255) & ~(size_t)255; };
    size_t off = 0;
    int*   degi = (int*)(ws + off);      off += align256((size_t)N * 4);
    float* stats = (float*)(ws + off);   off += align256(512 * 4);
    size_t zspan = off;                  // memset degi+stats in one shot
    float* dinv = (float*)(ws + off);    off += align256((size_t)N * 4);
    int*   rowstart = (int*)(ws + off);  off += align256((size_t)(N + 1) * 4);
    int*   cursor = (int*)(ws + off);    off += align256((size_t)N * 4);
    int*   blocksum = (int*)(ws + off);  off += align256(256 * 4);
    float* scsh = (float*)(ws + off);    off += align256(512 * 4);
    short* W1Th = (short*)(ws + off);    off += align256(32768 * 2);
    short* W1Tl = (short*)(ws + off);    off += align256(32768 * 2);
    short* W2Th = (short*)(ws + off);    off += align256(32768 * 2);
    short* W2Tl = (short*)(ws + off);    off += align256(32768 * 2);
    unsigned* csr = (unsigned*)(ws + off); off += align256((size_t)E * 4);
    short* nfb = (short*)(ws + off);     off += align256((size_t)N * CIN * 2);   // nf bf16
    short* agg1b = (short*)(ws + off);   off += align256((size_t)N * CIN * 2);   // S@x bf16
    short* x1b = (short*)(ws + off);     off += align256((size_t)N * CH * 2);    // layer1 bf16
    short* yb = (short*)(ws + off);      off += align256((size_t)N * COUT * 2);  // bnrelu(x1)@W2 bf16

    int nbN = (N + 255) / 256;
    int nbE = (E + 255) / 256;
    int n4 = N * 32;

    // zero degi + stats in one memset
    hipMemsetAsync(ws, 0, zspan, stream);

    // weight prep + feature cast (independent of graph build)
    k_prep<<<(65536 + n4 + 255) / 256, 256, 0, stream>>>(
        W1, W2, W1Th, W1Tl, W2Th, W2Tl, (const float4*)nf, (short4*)nfb, n4);

    // degree + norm + CSR build
    k_deg<<<nbE, 256, 0, stream>>>(dst, degi, E);
    k_scan1<<<nbN, 256, 0, stream>>>(degi, dinv, blocksum, N);
    k_scan3<<<nbN, 256, 0, stream>>>(degi, blocksum, nbN, rowstart, cursor, N, E);
    k_fill<<<nbE, 256, 0, stream>>>(src, dst, dinv, cursor, csr, E);

    // layer 1 aggregation (gather, bf16 in/out)
    k_gather<0><<<(N * 16 + 255) / 256, 256, 0, stream>>>(
        nfb, rowstart, csr, dinv, nullptr, nullptr, agg1b, N);

    // x1 = agg1 @ W1 + b1, fused BN stats
    k_gemm<CIN, CH, true, true, false><<<(N + 63) / 64, 256, 0, stream>>>(
        agg1b, W1Th, W1Tl, b1, nullptr, x1b, stats, N);

    // BN scale/shift
    k_bnfinal<<<1, 256, 0, stream>>>(stats, gamma, beta, scsh, N);

    // y = relu(bn(x1)) @ W2  (BN+ReLU fused into A-load; bias deferred to gather)
    k_gemm<CH, COUT, false, false, true><<<(N + 63) / 64, 256, 0, stream>>>(
        x1b, W2Th, W2Tl, nullptr, scsh, yb, nullptr, N);

    // out = S @ y + b2
    k_gather<1><<<(N * 16 + 255) / 256, 256, 0, stream>>>(
        yb, rowstart, csr, dinv, b2, out, nullptr, N);
}

// Round 8
// 299.890 us; speedup vs baseline: 10.2181x; 1.0640x over previous
//
#include <hip/hip_runtime.h>
#include <hip/hip_fp16.h>

#define CIN 128
#define CH 256
#define COUT 128
#define BN_EPS 1e-5f

typedef __attribute__((ext_vector_type(8))) short bf16x8;
typedef __attribute__((ext_vector_type(4))) float f32x4;

// float -> bf16 (round-to-nearest-even), raw short
__device__ __forceinline__ short f2bf(float x) {
    unsigned u = __float_as_uint(x);
    unsigned r = (u + 0x7fffu + ((u >> 16) & 1u)) >> 16;
    return (short)r;
}
__device__ __forceinline__ float bf2f(short h) {
    return __uint_as_float(((unsigned)(unsigned short)h) << 16);
}

// count in-degree; record each edge's rank within its dst bucket
__global__ void k_deg(const int* __restrict__ dst, int* __restrict__ degi,
                      unsigned short* __restrict__ rank, int E) {
    int e = blockIdx.x * 256 + threadIdx.x;
    if (e < E) rank[e] = (unsigned short)atomicAdd(&degi[dst[e]], 1);
}

// block sums of degi + fused dinv = rsqrt(deg+1)
__global__ void k_scan1(const int* __restrict__ degi, float* __restrict__ dinv,
                        int* __restrict__ blocksum, int N) {
    __shared__ int s[256];
    int i = blockIdx.x * 256 + threadIdx.x;
    int v = (i < N) ? degi[i] : 0;
    if (i < N) dinv[i] = rsqrtf((float)(v + 1));
    s[threadIdx.x] = v;
    __syncthreads();
    for (int st = 128; st > 0; st >>= 1) {
        if (threadIdx.x < st) s[threadIdx.x] += s[threadIdx.x + st];
        __syncthreads();
    }
    if (threadIdx.x == 0) blocksum[blockIdx.x] = s[0];
}

// per-element exclusive scan; every block redundantly scans blocksum in LDS. nb <= 256.
__global__ void k_scan3(const int* __restrict__ degi, const int* __restrict__ blocksum,
                        int nb, int* __restrict__ rowstart, int N, int E) {
    __shared__ int sb[256];
    __shared__ int s[256];
    int bv = (threadIdx.x < nb) ? blocksum[threadIdx.x] : 0;
    sb[threadIdx.x] = bv;
    __syncthreads();
    for (int st = 1; st < 256; st <<= 1) {
        int t = (threadIdx.x >= st) ? sb[threadIdx.x - st] : 0;
        __syncthreads();
        sb[threadIdx.x] += t;
        __syncthreads();
    }
    int boff = (blockIdx.x == 0) ? 0 : sb[blockIdx.x - 1];

    int i = blockIdx.x * 256 + threadIdx.x;
    int v = (i < N) ? degi[i] : 0;
    s[threadIdx.x] = v;
    __syncthreads();
    for (int st = 1; st < 256; st <<= 1) {
        int t = (threadIdx.x >= st) ? s[threadIdx.x - st] : 0;
        __syncthreads();
        s[threadIdx.x] += t;
        __syncthreads();
    }
    if (i < N) rowstart[i] = s[threadIdx.x] - v + boff;
    if (blockIdx.x == 0 && threadIdx.x == 0) rowstart[N] = E;
}

// atomic-free scatter: pos = rowstart[dst] + rank; 2-byte src record
__global__ void k_fill(const int* __restrict__ src, const int* __restrict__ dst,
                       const unsigned short* __restrict__ rank,
                       const int* __restrict__ rowstart,
                       unsigned short* __restrict__ csr, int E) {
    int e = blockIdx.x * 256 + threadIdx.x;
    if (e >= E) return;
    int d = dst[e];
    int pos = rowstart[d] + (int)rank[e];
    __builtin_nontemporal_store((unsigned short)src[e], &csr[pos]);
}

// fused: transpose+split W1,W2 and cast node features to bf16
__global__ void k_prep(const float* __restrict__ W1, const float* __restrict__ W2,
                       short* __restrict__ W1Th, short* __restrict__ W1Tl,
                       short* __restrict__ W2Th, short* __restrict__ W2Tl,
                       const float4* __restrict__ nf, short4* __restrict__ nfb, int n4) {
    int t = blockIdx.x * 256 + threadIdx.x;
    if (t < 32768) {                 // W1 [128][256] -> W1T [256][128]
        int n = t >> 7, k = t & 127;
        float v = W1[k * 256 + n];
        short h = f2bf(v);
        W1Th[t] = h;
        W1Tl[t] = f2bf(v - bf2f(h));
    } else if (t < 65536) {          // W2 [256][128] -> W2T [128][256]
        int u = t - 32768;
        int n = u >> 8, k = u & 255;
        float v = W2[k * 128 + n];
        short h = f2bf(v);
        W2Th[u] = h;
        W2Tl[u] = f2bf(v - bf2f(h));
    } else {
        int u = t - 65536;
        if (u < n4) {
            float4 v = nf[u];
            short4 s;
            s.x = f2bf(v.x); s.y = f2bf(v.y); s.z = f2bf(v.z); s.w = f2bf(v.w);
            nfb[u] = s;
        }
    }
}

// gather over CSR, bf16 input rows [N,128], fp32 accumulate.
// 16 lanes per row, 8 channels (16B) per lane; 8/4/1 edge unroll.
// Edge weight recomputed as dinv[src]*dinv[r] (fp32).
// MODE 0: write bf16 row; MODE 1: write fp32 + bias (final output)
template <int MODE>
__global__ __launch_bounds__(256) void k_gather(const short* __restrict__ xb,
                                                const int* __restrict__ rowstart,
                                                const unsigned short* __restrict__ csr,
                                                const float* __restrict__ dinv,
                                                const float* __restrict__ bias,
                                                float* __restrict__ out,
                                                short* __restrict__ ob, int N) {
    int t = blockIdx.x * 256 + threadIdx.x;
    int r = t >> 4;
    int c = t & 15;              // channels c*8 .. c*8+7
    if (r >= N) return;
    float di = dinv[r];
    float w0 = di * di;
    bf16x8 sv = *(const bf16x8*)(xb + (size_t)r * 128 + c * 8);
    float acc[8];
    #pragma unroll
    for (int j = 0; j < 8; ++j) acc[j] = bf2f(sv[j]) * w0;
    int e0 = rowstart[r], e1 = rowstart[r + 1];
    int e = e0;
    for (; e + 7 < e1; e += 8) {
        int s[8];
        #pragma unroll
        for (int i = 0; i < 8; ++i) s[i] = csr[e + i];
        float w[8];
        #pragma unroll
        for (int i = 0; i < 8; ++i) w[i] = dinv[s[i]] * di;
        bf16x8 x[8];
        #pragma unroll
        for (int i = 0; i < 8; ++i) x[i] = *(const bf16x8*)(xb + (size_t)s[i] * 128 + c * 8);
        #pragma unroll
        for (int i = 0; i < 8; ++i)
            #pragma unroll
            for (int j = 0; j < 8; ++j) acc[j] = fmaf(w[i], bf2f(x[i][j]), acc[j]);
    }
    for (; e + 3 < e1; e += 4) {
        int s[4];
        #pragma unroll
        for (int i = 0; i < 4; ++i) s[i] = csr[e + i];
        float w[4];
        #pragma unroll
        for (int i = 0; i < 4; ++i) w[i] = dinv[s[i]] * di;
        bf16x8 x[4];
        #pragma unroll
        for (int i = 0; i < 4; ++i) x[i] = *(const bf16x8*)(xb + (size_t)s[i] * 128 + c * 8);
        #pragma unroll
        for (int i = 0; i < 4; ++i)
            #pragma unroll
            for (int j = 0; j < 8; ++j) acc[j] = fmaf(w[i], bf2f(x[i][j]), acc[j]);
    }
    for (; e < e1; ++e) {
        int s0 = csr[e];
        float ww = dinv[s0] * di;
        bf16x8 x0 = *(const bf16x8*)(xb + (size_t)s0 * 128 + c * 8);
        #pragma unroll
        for (int j = 0; j < 8; ++j) acc[j] = fmaf(ww, bf2f(x0[j]), acc[j]);
    }
    if (MODE == 0) {
        bf16x8 h;
        #pragma unroll
        for (int j = 0; j < 8; ++j) h[j] = f2bf(acc[j]);
        *(bf16x8*)(ob + (size_t)r * 128 + c * 8) = h;
    } else {
        float4 b0 = *(const float4*)(bias + c * 8);
        float4 b1 = *(const float4*)(bias + c * 8 + 4);
        float4 o0 = make_float4(acc[0] + b0.x, acc[1] + b0.y, acc[2] + b0.z, acc[3] + b0.w);
        float4 o1 = make_float4(acc[4] + b1.x, acc[5] + b1.y, acc[6] + b1.z, acc[7] + b1.w);
        *(float4*)(out + (size_t)r * 128 + c * 8) = o0;
        *(float4*)(out + (size_t)r * 128 + c * 8 + 4) = o1;
    }
}

__device__ __forceinline__ bf16x8 bnrelu8(bf16x8 raw, const float* __restrict__ scsh, int c) {
    float4 sc0 = *(const float4*)(scsh + c);
    float4 sc1 = *(const float4*)(scsh + c + 4);
    float4 sh0 = *(const float4*)(scsh + 256 + c);
    float4 sh1 = *(const float4*)(scsh + 256 + c + 4);
    bf16x8 o;
    o[0] = f2bf(fmaxf(fmaf(bf2f(raw[0]), sc0.x, sh0.x), 0.f));
    o[1] = f2bf(fmaxf(fmaf(bf2f(raw[1]), sc0.y, sh0.y), 0.f));
    o[2] = f2bf(fmaxf(fmaf(bf2f(raw[2]), sc0.z, sh0.z), 0.f));
    o[3] = f2bf(fmaxf(fmaf(bf2f(raw[3]), sc0.w, sh0.w), 0.f));
    o[4] = f2bf(fmaxf(fmaf(bf2f(raw[4]), sc1.x, sh1.x), 0.f));
    o[5] = f2bf(fmaxf(fmaf(bf2f(raw[5]), sc1.y, sh1.y), 0.f));
    o[6] = f2bf(fmaxf(fmaf(bf2f(raw[6]), sc1.z, sh1.z), 0.f));
    o[7] = f2bf(fmaxf(fmaf(bf2f(raw[7]), sc1.w, sh1.w), 0.f));
    return o;
}

// C[M,NOUT](bf16) = f(A)[M,K](bf16) @ (Bh+Bl)^T[NOUT,K] + bias
// f = identity or BN+ReLU (scsh). Optional fused BN stats on output.
// Block: 256 thr = 4 waves, 64 rows x full NOUT. Wave: 64 rows x NOUT/4 cols.
// B-fragments preloaded to registers; epilogue staged via LDS for coalesced
// 16B row writes (avoids partial-sector write amplification).
template <int K, int NOUT, bool STATS, bool BIAS, bool BNRELU>
__global__ __launch_bounds__(256, 2) void k_gemm(const short* __restrict__ A,
                                                 const short* __restrict__ Bh,
                                                 const short* __restrict__ Bl,
                                                 const float* __restrict__ bias,
                                                 const float* __restrict__ scsh,
                                                 short* __restrict__ C,
                                                 float* __restrict__ stats, int M) {
    constexpr int CT = NOUT / 64;   // col-tiles per wave
    constexpr int KS = K / 32;      // k-steps
    constexpr int LROW = NOUT + 8;  // padded LDS row (shorts)
    __shared__ short lds[64 * LROW];
    int wave = threadIdx.x >> 6;
    int lane = threadIdx.x & 63;
    int m = lane & 15;
    int q = lane >> 4;
    int row0 = blockIdx.x * 64;
    int colw = wave * (NOUT / 4);

    // preload all B fragments for this wave into registers
    bf16x8 bhf[CT][KS], blf[CT][KS];
    #pragma unroll
    for (int ct = 0; ct < CT; ++ct) {
        #pragma unroll
        for (int ks = 0; ks < KS; ++ks) {
            size_t bo = (size_t)(colw + ct * 16 + m) * K + ks * 32 + q * 8;
            bhf[ct][ks] = *(const bf16x8*)(Bh + bo);
            blf[ct][ks] = *(const bf16x8*)(Bl + bo);
        }
    }

    const short* pa[4];
    #pragma unroll
    for (int rt = 0; rt < 4; ++rt) {
        int ar = row0 + rt * 16 + m;
        if (ar >= M) ar = M - 1;
        pa[rt] = A + (size_t)ar * K + q * 8;
    }

    f32x4 acc[4][CT];
    #pragma unroll
    for (int rt = 0; rt < 4; ++rt)
        #pragma unroll
        for (int ct = 0; ct < CT; ++ct)
            acc[rt][ct] = (f32x4){0.f, 0.f, 0.f, 0.f};

    #pragma unroll
    for (int ks = 0; ks < KS; ++ks) {
        bf16x8 af[4];
        #pragma unroll
        for (int rt = 0; rt < 4; ++rt) {
            bf16x8 raw = *(const bf16x8*)(pa[rt] + ks * 32);
            af[rt] = BNRELU ? bnrelu8(raw, scsh, ks * 32 + q * 8) : raw;
        }
        #pragma unroll
        for (int ct = 0; ct < CT; ++ct) {
            #pragma unroll
            for (int rt = 0; rt < 4; ++rt) {
                acc[rt][ct] = __builtin_amdgcn_mfma_f32_16x16x32_bf16(af[rt], bhf[ct][ks], acc[rt][ct], 0, 0, 0);
                acc[rt][ct] = __builtin_amdgcn_mfma_f32_16x16x32_bf16(af[rt], blf[ct][ks], acc[rt][ct], 0, 0, 0);
            }
        }
    }

    // epilogue: bias (+stats), bf16 -> LDS, then coalesced global writes
    #pragma unroll
    for (int ct = 0; ct < CT; ++ct) {
        int col = colw + ct * 16 + m;
        float bv = BIAS ? bias[col] : 0.f;
        float s = 0.f, sq = 0.f;
        #pragma unroll
        for (int rt = 0; rt < 4; ++rt) {
            #pragma unroll
            for (int r = 0; r < 4; ++r) {
                int lrow = rt * 16 + q * 4 + r;
                float v = acc[rt][ct][r] + bv;
                if (STATS && row0 + lrow < M) { s += v; sq = fmaf(v, v, sq); }
                lds[lrow * LROW + col] = f2bf(v);
            }
        }
        if (STATS) {
            s += __shfl_xor(s, 16, 64);
            s += __shfl_xor(s, 32, 64);
            sq += __shfl_xor(sq, 16, 64);
            sq += __shfl_xor(sq, 32, 64);
            if (lane < 16) {
                unsafeAtomicAdd(&stats[col], s);
                unsafeAtomicAdd(&stats[256 + col], sq);
            }
        }
    }
    __syncthreads();
    constexpr int CPR = NOUT / 8;       // 16B chunks per row
    constexpr int TOT = 64 * CPR;
    #pragma unroll
    for (int i = 0; i < TOT / 256; ++i) {
        int idx = i * 256 + threadIdx.x;
        int row = idx / CPR;
        int ch = idx % CPR;
        if (row0 + row < M)
            *(bf16x8*)(C + (size_t)(row0 + row) * NOUT + ch * 8) =
                *(const bf16x8*)(lds + row * LROW + ch * 8);
    }
}

__global__ void k_bnfinal(const float* __restrict__ stats, const float* __restrict__ gamma,
                          const float* __restrict__ beta, float* __restrict__ scsh, int N) {
    int c = threadIdx.x;
    float invN = 1.0f / (float)N;
    float mean = stats[c] * invN;
    float var = stats[256 + c] * invN - mean * mean;
    var = fmaxf(var, 0.f);
    float inv = rsqrtf(var + BN_EPS);
    float sc = gamma[c] * inv;
    scsh[c] = sc;
    scsh[256 + c] = fmaf(-mean, sc, beta[c]);
}

extern "C" void kernel_launch(void* const* d_in, const int* in_sizes, int n_in,
                              void* d_out, int out_size, void* d_ws, size_t ws_size,
                              hipStream_t stream) {
    const float* nf    = (const float*)d_in[0];
    const int*   ei    = (const int*)d_in[1];
    const float* W1    = (const float*)d_in[2];
    const float* b1    = (const float*)d_in[3];
    const float* gamma = (const float*)d_in[4];
    const float* beta  = (const float*)d_in[5];
    const float* W2    = (const float*)d_in[6];
    const float* b2    = (const float*)d_in[7];
    float* out = (float*)d_out;

    const int N = in_sizes[0] / CIN;      // 50000
    const int E = in_sizes[1] / 2;        // 800000
    const int* src = ei;
    const int* dst = ei + E;

    char* ws = (char*)d_ws;
    auto align256 = [](size_t x) { return (x + 255) & ~(size_t)255; };
    size_t off = 0;
    int*   degi = (int*)(ws + off);      off += align256((size_t)N * 4);
    float* stats = (float*)(ws + off);   off += align256(512 * 4);
    size_t zspan = off;                  // memset degi+stats in one shot
    float* dinv = (float*)(ws + off);    off += align256((size_t)N * 4);
    int*   rowstart = (int*)(ws + off);  off += align256((size_t)(N + 1) * 4);
    int*   blocksum = (int*)(ws + off);  off += align256(256 * 4);
    float* scsh = (float*)(ws + off);    off += align256(512 * 4);
    short* W1Th = (short*)(ws + off);    off += align256(32768 * 2);
    short* W1Tl = (short*)(ws + off);    off += align256(32768 * 2);
    short* W2Th = (short*)(ws + off);    off += align256(32768 * 2);
    short* W2Tl = (short*)(ws + off);    off += align256(32768 * 2);
    unsigned short* rank = (unsigned short*)(ws + off); off += align256((size_t)E * 2);
    unsigned short* csr = (unsigned short*)(ws + off);  off += align256((size_t)E * 2);
    short* nfb = (short*)(ws + off);     off += align256((size_t)N * CIN * 2);   // nf bf16
    short* agg1b = (short*)(ws + off);   off += align256((size_t)N * CIN * 2);   // S@x bf16
    short* x1b = (short*)(ws + off);     off += align256((size_t)N * CH * 2);    // layer1 bf16
    short* yb = (short*)(ws + off);      off += align256((size_t)N * COUT * 2);  // bnrelu(x1)@W2 bf16

    int nbN = (N + 255) / 256;
    int nbE = (E + 255) / 256;
    int n4 = N * 32;

    // zero degi + stats in one memset
    hipMemsetAsync(ws, 0, zspan, stream);

    // weight prep + feature cast (independent of graph build)
    k_prep<<<(65536 + n4 + 255) / 256, 256, 0, stream>>>(
        W1, W2, W1Th, W1Tl, W2Th, W2Tl, (const float4*)nf, (short4*)nfb, n4);

    // degree (+ per-edge rank) + norm + CSR build (atomic-free fill)
    k_deg<<<nbE, 256, 0, stream>>>(dst, degi, rank, E);
    k_scan1<<<nbN, 256, 0, stream>>>(degi, dinv, blocksum, N);
    k_scan3<<<nbN, 256, 0, stream>>>(degi, blocksum, nbN, rowstart, N, E);
    k_fill<<<nbE, 256, 0, stream>>>(src, dst, rank, rowstart, csr, E);

    // layer 1 aggregation (gather, bf16 in/out)
    k_gather<0><<<(N * 16 + 255) / 256, 256, 0, stream>>>(
        nfb, rowstart, csr, dinv, nullptr, nullptr, agg1b, N);

    // x1 = agg1 @ W1 + b1, fused BN stats
    k_gemm<CIN, CH, true, true, false><<<(N + 63) / 64, 256, 0, stream>>>(
        agg1b, W1Th, W1Tl, b1, nullptr, x1b, stats, N);

    // BN scale/shift
    k_bnfinal<<<1, 256, 0, stream>>>(stats, gamma, beta, scsh, N);

    // y = relu(bn(x1)) @ W2  (BN+ReLU fused into A-load; bias deferred to gather)
    k_gemm<CH, COUT, false, false, true><<<(N + 63) / 64, 256, 0, stream>>>(
        x1b, W2Th, W2Tl, nullptr, scsh, yb, nullptr, N);

    // out = S @ y + b2
    k_gather<1><<<(N * 16 + 255) / 256, 256, 0, stream>>>(
        yb, rowstart, csr, dinv, b2, out, nullptr, N);
}

// Round 9
// 276.856 us; speedup vs baseline: 11.0682x; 1.0832x over previous
//
#include <hip/hip_runtime.h>
#include <hip/hip_fp16.h>

#define CIN 128
#define CH 256
#define COUT 128
#define BN_EPS 1e-5f

typedef __attribute__((ext_vector_type(8))) short bf16x8;
typedef __attribute__((ext_vector_type(4))) float f32x4;

// float -> bf16 (round-to-nearest-even), raw short
__device__ __forceinline__ short f2bf(float x) {
    unsigned u = __float_as_uint(x);
    unsigned r = (u + 0x7fffu + ((u >> 16) & 1u)) >> 16;
    return (short)r;
}
__device__ __forceinline__ float bf2f(short h) {
    return __uint_as_float(((unsigned)(unsigned short)h) << 16);
}

// count in-degree; record each edge's rank within its dst bucket
__global__ void k_deg(const int* __restrict__ dst, int* __restrict__ degi,
                      unsigned short* __restrict__ rank, int E) {
    int e = blockIdx.x * 256 + threadIdx.x;
    if (e < E) rank[e] = (unsigned short)atomicAdd(&degi[dst[e]], 1);
}

// block sums of degi + fused dinv = rsqrt(deg+1)
__global__ void k_scan1(const int* __restrict__ degi, float* __restrict__ dinv,
                        int* __restrict__ blocksum, int N) {
    __shared__ int s[256];
    int i = blockIdx.x * 256 + threadIdx.x;
    int v = (i < N) ? degi[i] : 0;
    if (i < N) dinv[i] = rsqrtf((float)(v + 1));
    s[threadIdx.x] = v;
    __syncthreads();
    for (int st = 128; st > 0; st >>= 1) {
        if (threadIdx.x < st) s[threadIdx.x] += s[threadIdx.x + st];
        __syncthreads();
    }
    if (threadIdx.x == 0) blocksum[blockIdx.x] = s[0];
}

// per-element exclusive scan; every block redundantly scans blocksum in LDS. nb <= 256.
__global__ void k_scan3(const int* __restrict__ degi, const int* __restrict__ blocksum,
                        int nb, int* __restrict__ rowstart, int N, int E) {
    __shared__ int sb[256];
    __shared__ int s[256];
    int bv = (threadIdx.x < nb) ? blocksum[threadIdx.x] : 0;
    sb[threadIdx.x] = bv;
    __syncthreads();
    for (int st = 1; st < 256; st <<= 1) {
        int t = (threadIdx.x >= st) ? sb[threadIdx.x - st] : 0;
        __syncthreads();
        sb[threadIdx.x] += t;
        __syncthreads();
    }
    int boff = (blockIdx.x == 0) ? 0 : sb[blockIdx.x - 1];

    int i = blockIdx.x * 256 + threadIdx.x;
    int v = (i < N) ? degi[i] : 0;
    s[threadIdx.x] = v;
    __syncthreads();
    for (int st = 1; st < 256; st <<= 1) {
        int t = (threadIdx.x >= st) ? s[threadIdx.x - st] : 0;
        __syncthreads();
        s[threadIdx.x] += t;
        __syncthreads();
    }
    if (i < N) rowstart[i] = s[threadIdx.x] - v + boff;
    if (blockIdx.x == 0 && threadIdx.x == 0) rowstart[N] = E;
}

// atomic-free scatter: pos = rowstart[dst] + rank; 2-byte src record
__global__ void k_fill(const int* __restrict__ src, const int* __restrict__ dst,
                       const unsigned short* __restrict__ rank,
                       const int* __restrict__ rowstart,
                       unsigned short* __restrict__ csr, int E) {
    int e = blockIdx.x * 256 + threadIdx.x;
    if (e >= E) return;
    int d = dst[e];
    int pos = rowstart[d] + (int)rank[e];
    __builtin_nontemporal_store((unsigned short)src[e], &csr[pos]);
}

// fused prep:
//  - W1,W2 -> bf16 split (hi+lo), pre-swizzled into MFMA B-fragment order:
//    per (col16-tile, ks): 1KB block, lane L holds its bf16x8; hi at +0, lo at +512 shorts.
//  - node features -> bf16
__global__ void k_prep(const float* __restrict__ W1, const float* __restrict__ W2,
                       short* __restrict__ W1sw, short* __restrict__ W2sw,
                       const float4* __restrict__ nf, short4* __restrict__ nfb, int n4) {
    int t = blockIdx.x * 256 + threadIdx.x;
    if (t < 32768) {                 // W1 [128][256]: n=col (0..255), kk=k (0..127), KS=4
        int n = t >> 7, kk = t & 127;
        float v = W1[kk * 256 + n];
        short h = f2bf(v);
        short l = f2bf(v - bf2f(h));
        int t16 = n >> 4, m = n & 15;
        int ks = kk >> 5, q = (kk >> 3) & 3, j = kk & 7;
        int idx = (t16 * 4 + ks) * 1024 + (q * 16 + m) * 8 + j;
        W1sw[idx] = h;
        W1sw[idx + 512] = l;
    } else if (t < 65536) {          // W2 [256][128]: n=col (0..127), kk=k (0..255), KS=8
        int u = t - 32768;
        int n = u >> 8, kk = u & 255;
        float v = W2[kk * 128 + n];
        short h = f2bf(v);
        short l = f2bf(v - bf2f(h));
        int t16 = n >> 4, m = n & 15;
        int ks = kk >> 5, q = (kk >> 3) & 3, j = kk & 7;
        int idx = (t16 * 8 + ks) * 1024 + (q * 16 + m) * 8 + j;
        W2sw[idx] = h;
        W2sw[idx + 512] = l;
    } else {
        int u = t - 65536;
        if (u < n4) {
            float4 v = nf[u];
            short4 s;
            s.x = f2bf(v.x); s.y = f2bf(v.y); s.z = f2bf(v.z); s.w = f2bf(v.w);
            nfb[u] = s;
        }
    }
}

// gather over CSR, bf16 input rows [N,128], fp32 accumulate.
// 16 lanes per row, 8 channels (16B) per lane; 8/4/1 edge unroll.
// Edge weight recomputed as dinv[src]*dinv[r] (fp32).
// MODE 0: write bf16 row; MODE 1: write fp32 + bias (final output)
template <int MODE>
__global__ __launch_bounds__(256) void k_gather(const short* __restrict__ xb,
                                                const int* __restrict__ rowstart,
                                                const unsigned short* __restrict__ csr,
                                                const float* __restrict__ dinv,
                                                const float* __restrict__ bias,
                                                float* __restrict__ out,
                                                short* __restrict__ ob, int N) {
    int t = blockIdx.x * 256 + threadIdx.x;
    int r = t >> 4;
    int c = t & 15;              // channels c*8 .. c*8+7
    if (r >= N) return;
    float di = dinv[r];
    float w0 = di * di;
    bf16x8 sv = *(const bf16x8*)(xb + (size_t)r * 128 + c * 8);
    float acc[8];
    #pragma unroll
    for (int j = 0; j < 8; ++j) acc[j] = bf2f(sv[j]) * w0;
    int e0 = rowstart[r], e1 = rowstart[r + 1];
    int e = e0;
    for (; e + 7 < e1; e += 8) {
        int s[8];
        #pragma unroll
        for (int i = 0; i < 8; ++i) s[i] = csr[e + i];
        float w[8];
        #pragma unroll
        for (int i = 0; i < 8; ++i) w[i] = dinv[s[i]] * di;
        bf16x8 x[8];
        #pragma unroll
        for (int i = 0; i < 8; ++i) x[i] = *(const bf16x8*)(xb + (size_t)s[i] * 128 + c * 8);
        #pragma unroll
        for (int i = 0; i < 8; ++i)
            #pragma unroll
            for (int j = 0; j < 8; ++j) acc[j] = fmaf(w[i], bf2f(x[i][j]), acc[j]);
    }
    for (; e + 3 < e1; e += 4) {
        int s[4];
        #pragma unroll
        for (int i = 0; i < 4; ++i) s[i] = csr[e + i];
        float w[4];
        #pragma unroll
        for (int i = 0; i < 4; ++i) w[i] = dinv[s[i]] * di;
        bf16x8 x[4];
        #pragma unroll
        for (int i = 0; i < 4; ++i) x[i] = *(const bf16x8*)(xb + (size_t)s[i] * 128 + c * 8);
        #pragma unroll
        for (int i = 0; i < 4; ++i)
            #pragma unroll
            for (int j = 0; j < 8; ++j) acc[j] = fmaf(w[i], bf2f(x[i][j]), acc[j]);
    }
    for (; e < e1; ++e) {
        int s0 = csr[e];
        float ww = dinv[s0] * di;
        bf16x8 x0 = *(const bf16x8*)(xb + (size_t)s0 * 128 + c * 8);
        #pragma unroll
        for (int j = 0; j < 8; ++j) acc[j] = fmaf(ww, bf2f(x0[j]), acc[j]);
    }
    if (MODE == 0) {
        bf16x8 h;
        #pragma unroll
        for (int j = 0; j < 8; ++j) h[j] = f2bf(acc[j]);
        *(bf16x8*)(ob + (size_t)r * 128 + c * 8) = h;
    } else {
        float4 b0 = *(const float4*)(bias + c * 8);
        float4 b1 = *(const float4*)(bias + c * 8 + 4);
        float4 o0 = make_float4(acc[0] + b0.x, acc[1] + b0.y, acc[2] + b0.z, acc[3] + b0.w);
        float4 o1 = make_float4(acc[4] + b1.x, acc[5] + b1.y, acc[6] + b1.z, acc[7] + b1.w);
        *(float4*)(out + (size_t)r * 128 + c * 8) = o0;
        *(float4*)(out + (size_t)r * 128 + c * 8 + 4) = o1;
    }
}

__device__ __forceinline__ bf16x8 bnrelu8(bf16x8 raw, const float* __restrict__ scsh, int c) {
    float4 sc0 = *(const float4*)(scsh + c);
    float4 sc1 = *(const float4*)(scsh + c + 4);
    float4 sh0 = *(const float4*)(scsh + 256 + c);
    float4 sh1 = *(const float4*)(scsh + 256 + c + 4);
    bf16x8 o;
    o[0] = f2bf(fmaxf(fmaf(bf2f(raw[0]), sc0.x, sh0.x), 0.f));
    o[1] = f2bf(fmaxf(fmaf(bf2f(raw[1]), sc0.y, sh0.y), 0.f));
    o[2] = f2bf(fmaxf(fmaf(bf2f(raw[2]), sc0.z, sh0.z), 0.f));
    o[3] = f2bf(fmaxf(fmaf(bf2f(raw[3]), sc0.w, sh0.w), 0.f));
    o[4] = f2bf(fmaxf(fmaf(bf2f(raw[4]), sc1.x, sh1.x), 0.f));
    o[5] = f2bf(fmaxf(fmaf(bf2f(raw[5]), sc1.y, sh1.y), 0.f));
    o[6] = f2bf(fmaxf(fmaf(bf2f(raw[6]), sc1.z, sh1.z), 0.f));
    o[7] = f2bf(fmaxf(fmaf(bf2f(raw[7]), sc1.w, sh1.w), 0.f));
    return o;
}

// C[M,NOUT](bf16) = f(A)[M,K](bf16) @ W^T (split-bf16, fragment-swizzled) + bias
// f = identity or BN+ReLU (applied during LDS staging). Optional fused BN stats.
// Block: 256 thr = 4 waves, 64 rows x full NOUT; wave covers NOUT/4 cols (CT tiles).
// A-tile staged in LDS (padded rows, 2-way-free bank aliasing); fragments via
// ds_read_b128. B loads are single coalesced 16B/lane instructions (pre-swizzled).
// Epilogue staged via LDS (reused) for coalesced 16B row writes.
template <int K, int NOUT, bool STATS, bool BIAS, bool BNRELU>
__global__ __launch_bounds__(256, 2) void k_gemm(const short* __restrict__ A,
                                                 const short* __restrict__ Bsw,
                                                 const float* __restrict__ bias,
                                                 const float* __restrict__ scsh,
                                                 short* __restrict__ C,
                                                 float* __restrict__ stats, int M) {
    constexpr int CT = NOUT / 64;   // col16-tiles per wave
    constexpr int KS = K / 32;      // k-steps
    constexpr int KP = K + 8;       // padded A row (shorts)
    constexpr int LROW = NOUT + 8;  // padded epilogue row (shorts)
    constexpr int LSZ = (64 * KP > 64 * LROW) ? 64 * KP : 64 * LROW;
    __shared__ __align__(16) short lds[LSZ];
    int tid = threadIdx.x;
    int wave = tid >> 6;
    int lane = tid & 63;
    int m = lane & 15;
    int q = lane >> 4;
    int row0 = blockIdx.x * 64;

    // stage A-tile (64 x K) -> LDS, BN+ReLU fused here when enabled
    constexpr int CPRA = K / 8;     // 16B chunks per A row
    #pragma unroll
    for (int i = 0; i < (64 * CPRA) / 256; ++i) {
        int idx = i * 256 + tid;
        int r = idx / CPRA, cc = idx % CPRA;
        int gr = row0 + r;
        if (gr >= M) gr = M - 1;
        bf16x8 v = *(const bf16x8*)(A + (size_t)gr * K + cc * 8);
        if (BNRELU) v = bnrelu8(v, scsh, cc * 8);
        *(bf16x8*)(lds + r * KP + cc * 8) = v;
    }
    __syncthreads();

    f32x4 acc[4][CT];
    #pragma unroll
    for (int rt = 0; rt < 4; ++rt)
        #pragma unroll
        for (int ct = 0; ct < CT; ++ct)
            acc[rt][ct] = (f32x4){0.f, 0.f, 0.f, 0.f};

    #pragma unroll
    for (int ks = 0; ks < KS; ++ks) {
        // B fragments: coalesced 1KB blocks per (tile, ks), hi then lo
        bf16x8 bh[CT], bl[CT];
        #pragma unroll
        for (int ct = 0; ct < CT; ++ct) {
            const short* bp = Bsw + (size_t)((wave * CT + ct) * KS + ks) * 1024 + lane * 8;
            bh[ct] = *(const bf16x8*)bp;
            bl[ct] = *(const bf16x8*)(bp + 512);
        }
        // A fragments from LDS
        bf16x8 af[4];
        #pragma unroll
        for (int rt = 0; rt < 4; ++rt)
            af[rt] = *(const bf16x8*)(lds + (rt * 16 + m) * KP + ks * 32 + q * 8);
        #pragma unroll
        for (int ct = 0; ct < CT; ++ct)
            #pragma unroll
            for (int rt = 0; rt < 4; ++rt) {
                acc[rt][ct] = __builtin_amdgcn_mfma_f32_16x16x32_bf16(af[rt], bh[ct], acc[rt][ct], 0, 0, 0);
                acc[rt][ct] = __builtin_amdgcn_mfma_f32_16x16x32_bf16(af[rt], bl[ct], acc[rt][ct], 0, 0, 0);
            }
    }
    __syncthreads();   // A-tile reads done; reuse LDS for epilogue

    // epilogue: bias (+stats), bf16 -> LDS, then coalesced global writes
    #pragma unroll
    for (int ct = 0; ct < CT; ++ct) {
        int col = wave * (NOUT / 4) + ct * 16 + m;
        float bv = BIAS ? bias[col] : 0.f;
        float s = 0.f, sq = 0.f;
        #pragma unroll
        for (int rt = 0; rt < 4; ++rt) {
            #pragma unroll
            for (int r = 0; r < 4; ++r) {
                int lrow = rt * 16 + q * 4 + r;
                float v = acc[rt][ct][r] + bv;
                if (STATS && row0 + lrow < M) { s += v; sq = fmaf(v, v, sq); }
                lds[lrow * LROW + col] = f2bf(v);
            }
        }
        if (STATS) {
            s += __shfl_xor(s, 16, 64);
            s += __shfl_xor(s, 32, 64);
            sq += __shfl_xor(sq, 16, 64);
            sq += __shfl_xor(sq, 32, 64);
            if (lane < 16) {
                unsafeAtomicAdd(&stats[col], s);
                unsafeAtomicAdd(&stats[256 + col], sq);
            }
        }
    }
    __syncthreads();
    constexpr int CPR = NOUT / 8;       // 16B chunks per row
    #pragma unroll
    for (int i = 0; i < (64 * CPR) / 256; ++i) {
        int idx = i * 256 + tid;
        int row = idx / CPR;
        int ch = idx % CPR;
        if (row0 + row < M)
            *(bf16x8*)(C + (size_t)(row0 + row) * NOUT + ch * 8) =
                *(const bf16x8*)(lds + row * LROW + ch * 8);
    }
}

__global__ void k_bnfinal(const float* __restrict__ stats, const float* __restrict__ gamma,
                          const float* __restrict__ beta, float* __restrict__ scsh, int N) {
    int c = threadIdx.x;
    float invN = 1.0f / (float)N;
    float mean = stats[c] * invN;
    float var = stats[256 + c] * invN - mean * mean;
    var = fmaxf(var, 0.f);
    float inv = rsqrtf(var + BN_EPS);
    float sc = gamma[c] * inv;
    scsh[c] = sc;
    scsh[256 + c] = fmaf(-mean, sc, beta[c]);
}

extern "C" void kernel_launch(void* const* d_in, const int* in_sizes, int n_in,
                              void* d_out, int out_size, void* d_ws, size_t ws_size,
                              hipStream_t stream) {
    const float* nf    = (const float*)d_in[0];
    const int*   ei    = (const int*)d_in[1];
    const float* W1    = (const float*)d_in[2];
    const float* b1    = (const float*)d_in[3];
    const float* gamma = (const float*)d_in[4];
    const float* beta  = (const float*)d_in[5];
    const float* W2    = (const float*)d_in[6];
    const float* b2    = (const float*)d_in[7];
    float* out = (float*)d_out;

    const int N = in_sizes[0] / CIN;      // 50000
    const int E = in_sizes[1] / 2;        // 800000
    const int* src = ei;
    const int* dst = ei + E;

    char* ws = (char*)d_ws;
    auto align256 = [](size_t x) { return (x + 255) & ~(size_t)255; };
    size_t off = 0;
    int*   degi = (int*)(ws + off);      off += align256((size_t)N * 4);
    float* stats = (float*)(ws + off);   off += align256(512 * 4);
    size_t zspan = off;                  // memset degi+stats in one shot
    float* dinv = (float*)(ws + off);    off += align256((size_t)N * 4);
    int*   rowstart = (int*)(ws + off);  off += align256((size_t)(N + 1) * 4);
    int*   blocksum = (int*)(ws + off);  off += align256(256 * 4);
    float* scsh = (float*)(ws + off);    off += align256(512 * 4);
    short* W1sw = (short*)(ws + off);    off += align256(65536 * 2);   // swizzled hi+lo
    short* W2sw = (short*)(ws + off);    off += align256(65536 * 2);
    unsigned short* rank = (unsigned short*)(ws + off); off += align256((size_t)E * 2);
    unsigned short* csr = (unsigned short*)(ws + off);  off += align256((size_t)E * 2);
    short* nfb = (short*)(ws + off);     off += align256((size_t)N * CIN * 2);   // nf bf16
    short* agg1b = (short*)(ws + off);   off += align256((size_t)N * CIN * 2);   // S@x bf16
    short* x1b = (short*)(ws + off);     off += align256((size_t)N * CH * 2);    // layer1 bf16
    short* yb = (short*)(ws + off);      off += align256((size_t)N * COUT * 2);  // bnrelu(x1)@W2 bf16

    int nbN = (N + 255) / 256;
    int nbE = (E + 255) / 256;
    int n4 = N * 32;

    // zero degi + stats in one memset
    hipMemsetAsync(ws, 0, zspan, stream);

    // weight prep (swizzle+split) + feature cast (independent of graph build)
    k_prep<<<(65536 + n4 + 255) / 256, 256, 0, stream>>>(
        W1, W2, W1sw, W2sw, (const float4*)nf, (short4*)nfb, n4);

    // degree (+ per-edge rank) + norm + CSR build (atomic-free fill)
    k_deg<<<nbE, 256, 0, stream>>>(dst, degi, rank, E);
    k_scan1<<<nbN, 256, 0, stream>>>(degi, dinv, blocksum, N);
    k_scan3<<<nbN, 256, 0, stream>>>(degi, blocksum, nbN, rowstart, N, E);
    k_fill<<<nbE, 256, 0, stream>>>(src, dst, rank, rowstart, csr, E);

    // layer 1 aggregation (gather, bf16 in/out)
    k_gather<0><<<(N * 16 + 255) / 256, 256, 0, stream>>>(
        nfb, rowstart, csr, dinv, nullptr, nullptr, agg1b, N);

    // x1 = agg1 @ W1 + b1, fused BN stats
    k_gemm<CIN, CH, true, true, false><<<(N + 63) / 64, 256, 0, stream>>>(
        agg1b, W1sw, b1, nullptr, x1b, stats, N);

    // BN scale/shift
    k_bnfinal<<<1, 256, 0, stream>>>(stats, gamma, beta, scsh, N);

    // y = relu(bn(x1)) @ W2  (BN+ReLU fused into A staging; bias deferred to gather)
    k_gemm<CH, COUT, false, false, true><<<(N + 63) / 64, 256, 0, stream>>>(
        x1b, W2sw, nullptr, scsh, yb, nullptr, N);

    // out = S @ y + b2
    k_gather<1><<<(N * 16 + 255) / 256, 256, 0, stream>>>(
        yb, rowstart, csr, dinv, b2, out, nullptr, N);
}